// Round 14
// baseline (2158.076 us; speedup 1.0000x reference)
//
#include <hip/hip_runtime.h>

// CnnLstmPolicy: CNN(3 conv + fc) + scalar MLP -> LSTM (done-mask segmented) -> heads
// All GEMM-shaped compute via v_mfma_f32_16x16x32_bf16 (bf16 operands, f32 accum).
// Conv kernel: R13 structure (256 threads, (256,2), 74.5KB LDS, 2 blocks/CU) + free-
// register spending: persistent w2f, bias-in-accumulator (MFMA C-init), hoisted
// it-invariant addressing. LDS caps residency at 2 blocks/CU so VGPR<=256 is free.
// Tail: pack_all absorbs segprep+bias; fc+mlp fused into one heterogeneous launch.

typedef __attribute__((ext_vector_type(8))) short v8s;        // 8 x bf16 (4 VGPR)
typedef __attribute__((ext_vector_type(4))) float v4f;        // mfma accumulator
typedef __attribute__((ext_vector_type(4))) unsigned int v4u;

#define DEV static __device__ __forceinline__

DEV unsigned int cvtpk(float lo, float hi){
  unsigned int d;
  asm("v_cvt_pk_bf16_f32 %0, %1, %2" : "=v"(d) : "v"(lo), "v"(hi));  // RNE, S0->low
  return d;
}
DEV unsigned short f2bf(float x){ return (unsigned short)(cvtpk(x, x) & 0xffffu); }
DEV float bf2f(unsigned short h){ return __uint_as_float(((unsigned int)h) << 16); }
DEV unsigned int pkbf(float a, float b){ return cvtpk(a, b); }
DEV v4f MFMA(v8s a, v8s b, v4f c){ return __builtin_amdgcn_mfma_f32_16x16x32_bf16(a, b, c, 0, 0, 0); }
DEV v4f vzero(){ v4f z = {0.f, 0.f, 0.f, 0.f}; return z; }
DEV float relu(float x){ return x > 0.f ? x : 0.f; }
DEV float sigm(float x){ return 1.0f / (1.0f + __expf(-x)); }
DEV float tanhfast(float x){
  x = fminf(15.0f, fmaxf(-15.0f, x));
  float e = __expf(2.0f * x);
  return (e - 1.0f) / (e + 1.0f);
}
DEV uint2 pack4(v4f a, float4 b){  // (a+bias) -> relu -> 4x bf16 packed
  return make_uint2(cvtpk(relu(a[0]+b.x), relu(a[1]+b.y)),
                    cvtpk(relu(a[2]+b.z), relu(a[3]+b.w)));
}
DEV uint2 pack4r(v4f a){           // relu -> 4x bf16 packed (bias already in acc)
  return make_uint2(cvtpk(relu(a[0]), relu(a[1])),
                    cvtpk(relu(a[2]), relu(a[3])));
}
DEV v4f b2v4(float4 b){ v4f a; a[0]=b.x; a[1]=b.y; a[2]=b.z; a[3]=b.w; return a; }
union U8S { v4u u4; v8s s8; };

// ---------------- weight packing + segprep + bias (single launch) ----------------
// dst[(nt*KS+ks)*512 + lane*8 + e] = W[n][k], n = nt*16 + (lane&15), k = ks*32 + (lane>>4)*8 + e
// mode 0: direct  src[n*K + k]
// mode 1: conv    k = p9*CI + ci -> src[(n*CI+ci)*9 + p9]
// mode 2: fc      k = pos*64+ci  -> src[n*2560 + ci*40 + pos]
// mode 3: lstm    k<192: w_ih[n*192+k], else w_hh[n*128+k-192]
// mode 4: conv1   k = dy*8 + dx*2 + ci -> src[(n*2+ci)*9 + dy*3+dx]  (dx==3 / k>=K zero)
// block 3436: segprep (done-mask -> equal-length segment groups); block 3437: bias add
__global__ __launch_bounds__(256) void pack_all(
    const float* __restrict__ c1w, const float* __restrict__ c2w,
    const float* __restrict__ c3w, const float* __restrict__ fcw,
    const float* __restrict__ s1w, const float* __restrict__ s2w,
    const float* __restrict__ wih, const float* __restrict__ whh,
    const float* __restrict__ pw,
    unsigned short* __restrict__ w1p, unsigned short* __restrict__ w2p,
    unsigned short* __restrict__ w3p, unsigned short* __restrict__ fcp,
    unsigned short* __restrict__ s1p, unsigned short* __restrict__ s2p,
    unsigned short* __restrict__ lsp, unsigned short* __restrict__ pop,
    const void* __restrict__ dmask, const float* __restrict__ bih,
    const float* __restrict__ bhh, float* __restrict__ bias512,
    unsigned int* __restrict__ segs, int4* __restrict__ gtab, int* __restrict__ meta){
  __shared__ int sp[772];   // segprep scratch: cnt[257], off[257], place[257], notInt
  int b = blockIdx.x;
  int tid = threadIdx.x;
  if (b == 3437){
    bias512[tid] = bih[tid] + bhh[tid];
    bias512[tid + 256] = bih[tid + 256] + bhh[tid + 256];
    return;
  }
  if (b == 3436){
    int* cnt = sp; int* off = sp + 257; int* place = sp + 514;
    for (int idx = tid; idx < 257; idx += 256){ cnt[idx] = 0; place[idx] = 0; }
    if (tid == 0) sp[771] = 0;
    __syncthreads();
    const unsigned char* p8 = (const unsigned char*)dmask;
    int nz = 0;
    for (int idx = tid; idx < 2048; idx += 256)
      if (p8[idx * 4 + 1] | p8[idx * 4 + 2] | p8[idx * 4 + 3]) nz = 1;
    if (nz) sp[771] = 1;
    __syncthreads();
    bool m32 = (sp[771] == 0);
    const int* p32 = (const int*)dmask;
    if (tid < 128){
      int bb = tid, ts = 0;
      for (int t = 0; t < 256; ++t){
        bool d = (t == 255) ? true : (m32 ? (p32[t * 128 + bb] != 0) : (p8[t * 128 + bb] != 0));
        if (d){ atomicAdd(&cnt[t - ts + 1], 1); ts = t + 1; }
      }
    }
    __syncthreads();
    if (tid == 0){
      int acc = 0;
      for (int len = 1; len <= 256; ++len){ off[len] = acc; acc += cnt[len]; }
      int G = 0;
      for (int len = 1; len <= 256; ++len){
        int c = cnt[len], g = 0;
        while (c > 0){
          int take = c < 32 ? c : 32;
          gtab[G] = make_int4(len, off[len] + g * 32, take, 0);
          ++G; c -= 32; ++g;
        }
      }
      meta[0] = G;
    }
    __syncthreads();
    if (tid < 128){
      int bb = tid, ts = 0;
      for (int t = 0; t < 256; ++t){
        bool d = (t == 255) ? true : (m32 ? (p32[t * 128 + bb] != 0) : (p8[t * 128 + bb] != 0));
        if (d){
          int len = t - ts + 1;
          int slot = off[len] + atomicAdd(&place[len], 1);
          segs[slot] = (unsigned int)(bb | (ts << 8));
          ts = t + 1;
        }
      }
    }
    return;
  }
  const float *src, *src2 = nullptr; unsigned short* dst;
  int N, K, KS, CI, mode, rel;
  if      (b < 4)   { src=c1w; dst=w1p; N=32;  K=24;  KS=1;  CI=2;  mode=4; rel=b; }
  else if (b < 76)  { src=c2w; dst=w2p; N=64;  K=288; KS=9;  CI=32; mode=1; rel=b-4; }
  else if (b < 220) { src=c3w; dst=w3p; N=64;  K=576; KS=18; CI=64; mode=1; rel=b-76; }
  else if (b < 1500){ src=fcw; dst=fcp; N=128; K=2560;KS=80; CI=0;  mode=2; rel=b-220; }
  else if (b < 1620){ src=s1w; dst=s1p; N=64;  K=452; KS=15; CI=0;  mode=0; rel=b-1500; }
  else if (b < 1636){ src=s2w; dst=s2p; N=64;  K=64;  KS=2;  CI=0;  mode=0; rel=b-1620; }
  else if (b < 2276){ src=wih; src2=whh; dst=lsp; N=512; K=320; KS=10; CI=0; mode=3; rel=b-1636; }
  else              { src=pw;  dst=pop; N=2305;K=128; KS=4;  CI=0;  mode=0; rel=b-2276; }
  int idx = rel * 256 + tid;
  int e  = idx & 7;
  int l  = (idx >> 3) & 63;
  int fs = idx >> 9;
  int ks = fs % KS;
  int nt = fs / KS;
  int n = nt * 16 + (l & 15);
  int k = ks * 32 + (l >> 4) * 8 + e;
  float v = 0.f;
  if (n < N && k < K){
    if (mode == 0)      v = src[n * K + k];
    else if (mode == 1){ int p9 = k / CI, ci = k - p9 * CI; v = src[(n * CI + ci) * 9 + p9]; }
    else if (mode == 2){ int pos = k >> 6, ci = k & 63;     v = src[n * 2560 + ci * 40 + pos]; }
    else if (mode == 3) v = (k < 192) ? src[n * 192 + k] : src2[n * 128 + (k - 192)];
    else { int dy = k >> 3, r = k & 7, dx = r >> 1, ci = r & 1;
           if (dx < 3) v = src[(n * 2 + ci) * 9 + dy * 3 + dx]; }
  }
  dst[idx] = f2bf(v);
}

// ---------------- fused conv1/conv2/conv3 per sample (R13 + register spending) ----------------
// LDS map (all zeroed once; halos never rewritten):
//  ACT1: [34 rows][20 cols][32ch] bf16  = 43520 B, swizzle ^(((p>>1)&7)<<4)
//  ACT2: [18 rows][11 cols][64ch] bf16  = 25344 B, swizzle ^(((p>>1)&7)<<4)
//  GRID: 2 x [35 rows][20 cols] u32 (ch0 lo, ch1 hi) = 2 x 2816 B, linear
#define ACT1o 0
#define ACT2o 43520
#define GRIDo 68864
#define SWZ(p) ((((p) >> 1) & 7) << 4)

__global__ __launch_bounds__(256, 2) void conv_kernel(const float* __restrict__ obs,
    const unsigned short* __restrict__ w1p, const unsigned short* __restrict__ w2p,
    const unsigned short* __restrict__ w3p,
    const float* __restrict__ b1v, const float* __restrict__ b2v, const float* __restrict__ b3v,
    unsigned short* __restrict__ act3g){
  __shared__ __align__(16) char lds[74496];
  int tid = threadIdx.x, w = tid >> 6, l = tid & 63, i = l & 15, u = l >> 4;
  int nh = w & 1, mh = w >> 1;
  const v8s* W1 = (const v8s*)w1p;
  const v8s* W2 = (const v8s*)w2p;
  const v8s* W3 = (const v8s*)w3p;
  v8s w1f0 = W1[l], w1f1 = W1[64 + l];              // persistent conv1 weights
  v8s w2f[2][9];                                     // persistent conv2 weights
  #pragma unroll
  for (int jj = 0; jj < 2; ++jj)
    #pragma unroll
    for (int t = 0; t < 9; ++t) w2f[jj][t] = W2[((nh * 2 + jj) * 9 + t) * 64 + l];
  v4f bv1a = b2v4(*(const float4*)&b1v[u * 4]);
  v4f bv1b = b2v4(*(const float4*)&b1v[16 + u * 4]);
  v4f bv2a = b2v4(*(const float4*)&b2v[nh * 32 + u * 4]);
  v4f bv2b = b2v4(*(const float4*)&b2v[nh * 32 + 16 + u * 4]);
  v4f bv3a = b2v4(*(const float4*)&b3v[nh * 32 + u * 4]);
  v4f bv3b = b2v4(*(const float4*)&b3v[nh * 32 + 16 + u * 4]);
  // zero ALL of LDS once (covers halos + grid pad rows)
  for (int idx = tid; idx < 18624; idx += 256) *(unsigned int*)(lds + idx * 4) = 0u;
  // staging offsets: thread tid<144 owns pixels 4tid..4tid+3 -> padded [r+1][c+1]
  int soff[4];
  #pragma unroll
  for (int j = 0; j < 4; ++j){
    int p = tid * 4 + j, r = p / 18, c = p - r * 18;
    soff[j] = ((r + 1) * 20 + (c + 1)) * 4;
  }
  __syncthreads();
  long sbase = (long)blockIdx.x * 64;
  if (tid < 144){
    const float4* gp = (const float4*)(obs + sbase * 1604 + 452);
    float4 a = gp[tid], b = gp[tid + 144];
    *(unsigned int*)(lds + GRIDo + soff[0]) = pkbf(a.x, b.x);
    *(unsigned int*)(lds + GRIDo + soff[1]) = pkbf(a.y, b.y);
    *(unsigned int*)(lds + GRIDo + soff[2]) = pkbf(a.z, b.z);
    *(unsigned int*)(lds + GRIDo + soff[3]) = pkbf(a.w, b.w);
  }
  __syncthreads();

  // ---- it-invariant hoisted geometry ----
  // conv1: 9 pos-tiles per wave -> grid-read offsets + ACT1 write offsets
  int goffk[9], wAk[9], wBk[9];
  #pragma unroll
  for (int k = 0; k < 9; ++k){
    int ntl = w + 4 * k;
    int pos = ntl * 16 + i;
    int oh = pos / 18, ow = pos - oh * 18;
    goffk[k] = ((oh + u) * 20 + ow) * 4;
    int p1 = (oh + 1) * 20 + (ow + 1);
    wAk[k] = ACT1o + ((p1 * 64 + u * 8) ^ SWZ(p1));
    wBk[k] = ACT1o + ((p1 * 64 + 32 + u * 8) ^ SWZ(p1));
  }
  // conv2: up to 5 pos-tiles (ntl = mh + 2k < 9)
  int pr2k[5], w2Ak[5], w2Bk[5];
  #pragma unroll
  for (int kk = 0; kk < 5; ++kk){
    int ntl = mh + 2 * kk;
    int ntc = ntl < 9 ? ntl : 0;
    int pos2 = ntc * 16 + i;
    int oh = pos2 / 9, ow = pos2 - oh * 9;
    pr2k[kk] = (2 * oh) * 20 + 2 * ow;
    int p2 = (oh + 1) * 11 + (ow + 1);
    w2Ak[kk] = ACT2o + ((p2 * 128 + nh * 64 + u * 8) ^ SWZ(p2));
    w2Bk[kk] = w2Ak[kk] ^ 32;   // +32 bytes: bit5 untouched by SWZ (bits 4..6 on *128 grid)? compute safely below
  }
  // recompute w2Bk exactly (XOR trick unsafe in general)
  #pragma unroll
  for (int kk = 0; kk < 5; ++kk){
    int ntl = mh + 2 * kk;
    int ntc = ntl < 9 ? ntl : 0;
    int pos2 = ntc * 16 + i;
    int oh = pos2 / 9, ow = pos2 - oh * 9;
    int p2 = (oh + 1) * 11 + (ow + 1);
    w2Bk[kk] = ACT2o + ((p2 * 128 + nh * 64 + 32 + u * 8) ^ SWZ(p2));
  }
  // conv3 geometry
  int pos3_0 = (mh ? 1 : 0) * 16 + i;
  int pos3_1r = 32 + i;
  int pos3_1 = pos3_1r > 39 ? 39 : pos3_1r;
  int oh30 = pos3_0 / 5, ow30 = pos3_0 - oh30 * 5;
  int oh31 = pos3_1 / 5, ow31 = pos3_1 - oh31 * 5;
  int pr3_0 = (2 * oh30) * 11 + 2 * ow30;
  int pr3_1 = (2 * oh31) * 11 + 2 * ow31;

  for (int it = 0; it < 64; ++it){
    long s = sbase + it;
    int gbo = GRIDo + (it & 1) * 2816;
    // prefetch next sample's grid
    float4 pa, pb; bool pf = (it < 63) && (tid < 144);
    if (pf){
      const float4* gp = (const float4*)(obs + (s + 1) * 1604 + 452);
      pa = gp[tid]; pb = gp[tid + 144];
    }
    // ---- conv1: fragments straight from padded grid; bias in C-init ----
    #pragma unroll
    for (int k = 0; k < 9; ++k){
      int glin = gbo + goffk[k];
      U8S gv;
      gv.u4.x = *(const unsigned int*)(lds + glin);
      gv.u4.y = *(const unsigned int*)(lds + glin + 4);
      gv.u4.z = *(const unsigned int*)(lds + glin + 8);
      gv.u4.w = *(const unsigned int*)(lds + glin + 12);
      v4f a0 = MFMA(w1f0, gv.s8, bv1a);
      v4f a1 = MFMA(w1f1, gv.s8, bv1b);
      *(uint2*)(lds + wAk[k]) = pack4r(a0);
      *(uint2*)(lds + wBk[k]) = pack4r(a1);
    }
    __syncthreads();   // B: ACT1 visible; grid reads done
    // ---- conv2: hoisted geometry, persistent weights, bias in C-init ----
    #pragma unroll
    for (int kk = 0; kk < 5; ++kk){
      if (mh + 2 * kk < 9){
        v4f a0 = bv2a, a1 = bv2b;
        #pragma unroll
        for (int dy = 0; dy < 3; ++dy)
          #pragma unroll
          for (int dx = 0; dx < 3; ++dx){
            int p = pr2k[kk] + dy * 20 + dx;
            int byte = (p * 64 + u * 16) ^ SWZ(p);
            v8s bf = *(const v8s*)(lds + ACT1o + byte);
            a0 = MFMA(w2f[0][dy * 3 + dx], bf, a0);
            a1 = MFMA(w2f[1][dy * 3 + dx], bf, a1);
          }
        *(uint2*)(lds + w2Ak[kk]) = pack4r(a0);
        *(uint2*)(lds + w2Bk[kk]) = pack4r(a1);
      }
    }
    // stage next sample's grid into the other buffer (visible after barrier C)
    if (pf){
      int gbn = GRIDo + ((it + 1) & 1) * 2816;
      *(unsigned int*)(lds + gbn + soff[0]) = pkbf(pa.x, pb.x);
      *(unsigned int*)(lds + gbn + soff[1]) = pkbf(pa.y, pb.y);
      *(unsigned int*)(lds + gbn + soff[2]) = pkbf(pa.z, pb.z);
      *(unsigned int*)(lds + gbn + soff[3]) = pkbf(pa.w, pb.w);
    }
    __syncthreads();   // C: ACT2 + next grid visible
    // ---- conv3: ch-pair nh x pos-split mh; K in 2 chunks (phase-local w3 reloads) ----
    {
      int z3; asm("s_mov_b32 %0, 0" : "=s"(z3) : "s"(it));
      v4f c300 = bv3a, c301 = bv3b, c310 = bv3a, c311 = bv3b;
      #pragma unroll
      for (int ksh = 0; ksh < 2; ++ksh){
        const int t0 = ksh * 5, tc = ksh ? 4 : 5;
        v8s w3q[2][5][2];
        #pragma unroll
        for (int j = 0; j < 2; ++j)
          #pragma unroll
          for (int tt = 0; tt < 5; ++tt){
            if (tt < tc){
              #pragma unroll
              for (int h = 0; h < 2; ++h)
                w3q[j][tt][h] = W3[((2 * nh + j) * 18 + 2 * (t0 + tt) + h) * 64 + l + z3];
            }
          }
        #pragma unroll
        for (int tt = 0; tt < 5; ++tt){
          if (tt < tc){
            int tap = t0 + tt, dy = tap / 3, dx = tap - dy * 3;
            int dpp = dy * 11 + dx;
            #pragma unroll
            for (int h = 0; h < 2; ++h){
              {
                int p = pr3_0 + dpp;
                int byte = (p * 128 + h * 64 + u * 16) ^ SWZ(p);
                v8s bf = *(const v8s*)(lds + ACT2o + byte);
                c300 = MFMA(w3q[0][tt][h], bf, c300);
                c301 = MFMA(w3q[1][tt][h], bf, c301);
              }
              if (mh == 0){
                int p = pr3_1 + dpp;
                int byte = (p * 128 + h * 64 + u * 16) ^ SWZ(p);
                v8s bf = *(const v8s*)(lds + ACT2o + byte);
                c310 = MFMA(w3q[0][tt][h], bf, c310);
                c311 = MFMA(w3q[1][tt][h], bf, c311);
              }
            }
          }
        }
      }
      unsigned short* dg = act3g + s * 2560;
      *(uint2*)(dg + pos3_0 * 64 + nh * 32 + u * 4)      = pack4r(c300);
      *(uint2*)(dg + pos3_0 * 64 + nh * 32 + 16 + u * 4) = pack4r(c301);
      if (mh == 0 && pos3_1r < 40){
        *(uint2*)(dg + pos3_1r * 64 + nh * 32 + u * 4)      = pack4r(c310);
        *(uint2*)(dg + pos3_1r * 64 + nh * 32 + 16 + u * 4) = pack4r(c311);
      }
    }
    // no trailing barrier: conv3's ACT2 reads are protected by next iteration's barrier B
  }
}

// ---------------- embed: fc (blocks 0..511) + scalar MLP (blocks 512..1535) ----------------
__global__ __launch_bounds__(256) void embed_kernel(
    const unsigned short* __restrict__ act3g, const unsigned short* __restrict__ fcp,
    const float* __restrict__ fcb,
    const float* __restrict__ obs, const unsigned short* __restrict__ s1p,
    const unsigned short* __restrict__ s2p,
    const float* __restrict__ s1b, const float* __restrict__ s2b,
    unsigned short* __restrict__ emb){
  __shared__ __align__(16) unsigned short shb[17920];
  int bid = blockIdx.x;
  int tid = threadIdx.x, w = tid >> 6, l = tid & 63, i = l & 15, u = l >> 4;
  if (bid < 512){
    // ---- fc: act3(2560) -> 128, relu -> emb[:,0:128] ----
    unsigned short* al = shb;                        // [64 rows][264]
    long s0 = (long)bid * 64;
    v4f acc[4][2];
    #pragma unroll
    for (int mt = 0; mt < 4; ++mt){ acc[mt][0] = vzero(); acc[mt][1] = vzero(); }
    const v8s* F = (const v8s*)fcp;
    for (int kc = 0; kc < 10; ++kc){
      __syncthreads();
      for (int idx = tid; idx < 64 * 32; idx += 256){
        int r = idx >> 5, q = idx & 31;
        *(v8s*)&al[r * 264 + q * 8] = *(const v8s*)&act3g[(s0 + r) * 2560 + kc * 256 + q * 8];
      }
      __syncthreads();
      #pragma unroll
      for (int ksl = 0; ksl < 8; ++ksl){
        v8s b0 = F[((w * 2 + 0) * 80 + kc * 8 + ksl) * 64 + l];
        v8s b1 = F[((w * 2 + 1) * 80 + kc * 8 + ksl) * 64 + l];
        #pragma unroll
        for (int mt = 0; mt < 4; ++mt){
          v8s aa = *(const v8s*)&al[(mt * 16 + i) * 264 + ksl * 32 + u * 8];
          acc[mt][0] = MFMA(aa, b0, acc[mt][0]);
          acc[mt][1] = MFMA(aa, b1, acc[mt][1]);
        }
      }
    }
    float fb0 = fcb[(w * 2) * 16 + i], fb1 = fcb[(w * 2 + 1) * 16 + i];
    #pragma unroll
    for (int mt = 0; mt < 4; ++mt)
      #pragma unroll
      for (int r = 0; r < 4; ++r){
        float v0 = relu(acc[mt][0][r] + fb0);
        float v1 = relu(acc[mt][1][r] + fb1);
        emb[(s0 + mt * 16 + u * 4 + r) * 192 + (w * 2) * 16 + i] = f2bf(v0);
        emb[(s0 + mt * 16 + u * 4 + r) * 192 + (w * 2 + 1) * 16 + i] = f2bf(v1);
      }
  } else {
    // ---- scalar MLP: obs[:,:452] -> 64 -> 64 -> emb[:,128:192] ----
    unsigned short* xl = shb;                        // [32 rows][488]
    unsigned short* h1 = shb + 15616;                // [32 rows][72]
    long s0 = (long)(bid - 512) * 32;
    for (int idx = tid; idx < 32 * 113; idx += 256){
      int r = idx / 113, q = idx - r * 113;
      float4 v = *(const float4*)&obs[(s0 + r) * 1604 + q * 4];
      *(uint2*)&xl[r * 488 + q * 4] = make_uint2(pkbf(v.x, v.y), pkbf(v.z, v.w));
    }
    for (int idx = tid; idx < 32 * 28; idx += 256){   // zero pad cols 452..479
      int r = idx / 28, k = 452 + (idx - r * 28);
      xl[r * 488 + k] = 0;
    }
    __syncthreads();
    v4f acc0 = vzero(), acc1 = vzero();
    const v8s* F1 = (const v8s*)s1p;
    #pragma unroll
    for (int ks = 0; ks < 15; ++ks){
      v8s bb = F1[(w * 15 + ks) * 64 + l];
      v8s aa0 = *(const v8s*)&xl[(0 * 16 + i) * 488 + ks * 32 + u * 8];
      v8s aa1 = *(const v8s*)&xl[(1 * 16 + i) * 488 + ks * 32 + u * 8];
      acc0 = MFMA(aa0, bb, acc0);
      acc1 = MFMA(aa1, bb, acc1);
    }
    float b1 = s1b[w * 16 + i];
    #pragma unroll
    for (int r = 0; r < 4; ++r){
      float v0 = relu(acc0[r] + b1);
      float v1 = relu(acc1[r] + b1);
      h1[(u * 4 + r) * 72 + w * 16 + i] = f2bf(v0);
      h1[(16 + u * 4 + r) * 72 + w * 16 + i] = f2bf(v1);
    }
    __syncthreads();
    v4f a20 = vzero(), a21 = vzero();
    const v8s* F2 = (const v8s*)s2p;
    #pragma unroll
    for (int ks = 0; ks < 2; ++ks){
      v8s bb = F2[(w * 2 + ks) * 64 + l];
      v8s aa0 = *(const v8s*)&h1[(0 * 16 + i) * 72 + ks * 32 + u * 8];
      v8s aa1 = *(const v8s*)&h1[(1 * 16 + i) * 72 + ks * 32 + u * 8];
      a20 = MFMA(aa0, bb, a20);
      a21 = MFMA(aa1, bb, a21);
    }
    float b2 = s2b[w * 16 + i];
    #pragma unroll
    for (int r = 0; r < 4; ++r){
      float v0 = relu(a20[r] + b2);
      float v1 = relu(a21[r] + b2);
      emb[(s0 + u * 4 + r) * 192 + 128 + w * 16 + i] = f2bf(v0);
      emb[(s0 + 16 + u * 4 + r) * 192 + 128 + w * 16 + i] = f2bf(v1);
    }
  }
}

// ---------------- LSTM over segment groups: M=32 segs, N=512 gates, K=320 ----------------
__global__ __launch_bounds__(512) void lstm_kernel(
    const unsigned short* __restrict__ emb, const unsigned short* __restrict__ lstmp,
    const float* __restrict__ bias512,
    const float* __restrict__ h0, const float* __restrict__ c0,
    const unsigned int* __restrict__ segs, const int4* __restrict__ gtab,
    const int* __restrict__ meta,
    unsigned short* __restrict__ outsb, float* __restrict__ hf, float* __restrict__ cf){
  int grp = blockIdx.x;
  if (grp >= meta[0]) return;
  int4 gd = gtab[grp];
  int len = gd.x, base = gd.y, nseg = gd.z;
  __shared__ __align__(16) unsigned short hbuf[2][32 * 136];
  __shared__ int sb[32], st[32];
  int tid = threadIdx.x, w = tid >> 6, l = tid & 63, i = l & 15, u = l >> 4;
  if (tid < 32){
    unsigned int sv = segs[base + (tid < nseg ? tid : 0)];
    sb[tid] = (int)(sv & 127u);
    st[tid] = (int)((sv >> 8) & 255u);
  }
  __syncthreads();
  int j = w * 16 + i;
  float cst[2][4];
  #pragma unroll
  for (int mt = 0; mt < 2; ++mt)
    #pragma unroll
    for (int r = 0; r < 4; ++r){
      int slot = mt * 16 + u * 4 + r;
      float cv = 0.f, hv = 0.f;
      if (st[slot] == 0){ cv = c0[sb[slot] * 128 + j]; hv = h0[sb[slot] * 128 + j]; }
      cst[mt][r] = cv;
      hbuf[0][slot * 136 + j] = f2bf(hv);
    }
  float bi = bias512[j], bff = bias512[128 + j], bg = bias512[256 + j], bo = bias512[384 + j];
  int bA0 = sb[i], tA0 = st[i];
  int bA1 = sb[16 + i], tA1 = st[16 + i];
  __syncthreads();
  const v8s* LP = (const v8s*)lstmp;
  for (int step = 0; step < len; ++step){
    int pb = step & 1;
    v4f gi0 = vzero(), gi1 = vzero(), gf0 = vzero(), gf1 = vzero();
    v4f gg0 = vzero(), gg1 = vzero(), go0 = vzero(), go1 = vzero();
    #pragma unroll
    for (int ks = 0; ks < 10; ++ks){
      v8s a0, a1;
      if (ks < 6){
        a0 = *(const v8s*)&emb[((long)(tA0 + step) * 128 + bA0) * 192 + ks * 32 + u * 8];
        a1 = *(const v8s*)&emb[((long)(tA1 + step) * 128 + bA1) * 192 + ks * 32 + u * 8];
      } else {
        int koff = (ks - 6) * 32 + u * 8;
        a0 = *(const v8s*)&hbuf[pb][i * 136 + koff];
        a1 = *(const v8s*)&hbuf[pb][(16 + i) * 136 + koff];
      }
      v8s b_i = LP[((w) * 10 + ks) * 64 + l];
      v8s b_f = LP[((w + 8) * 10 + ks) * 64 + l];
      v8s b_g = LP[((w + 16) * 10 + ks) * 64 + l];
      v8s b_o = LP[((w + 24) * 10 + ks) * 64 + l];
      gi0 = MFMA(a0, b_i, gi0); gi1 = MFMA(a1, b_i, gi1);
      gf0 = MFMA(a0, b_f, gf0); gf1 = MFMA(a1, b_f, gf1);
      gg0 = MFMA(a0, b_g, gg0); gg1 = MFMA(a1, b_g, gg1);
      go0 = MFMA(a0, b_o, go0); go1 = MFMA(a1, b_o, go1);
    }
    #pragma unroll
    for (int mt = 0; mt < 2; ++mt)
      #pragma unroll
      for (int r = 0; r < 4; ++r){
        int slot = mt * 16 + u * 4 + r;
        float giv = mt ? gi1[r] : gi0[r];
        float gfv = mt ? gf1[r] : gf0[r];
        float ggv = mt ? gg1[r] : gg0[r];
        float gov = mt ? go1[r] : go0[r];
        float iv = sigm(giv + bi);
        float fv = sigm(gfv + bff);
        float gv = tanhfast(ggv + bg);
        float ov = sigm(gov + bo);
        float cv = fv * cst[mt][r] + iv * gv;
        cst[mt][r] = cv;
        float hv = ov * tanhfast(cv);
        unsigned short hb = f2bf(hv);
        hbuf[pb ^ 1][slot * 136 + j] = hb;
        if (slot < nseg){
          outsb[((long)(st[slot] + step) * 128 + sb[slot]) * 128 + j] = hb;
          if (st[slot] + len == 256 && step == len - 1){
            hf[sb[slot] * 128 + j] = hv;
            cf[sb[slot] * 128 + j] = cv;
          }
        }
      }
    __syncthreads();
  }
}

// ---------------- heads: logits = outs @ pol_w.T + pol_b; values fused ----------------
__global__ __launch_bounds__(256) void heads_kernel(const unsigned short* __restrict__ outsb,
    const unsigned short* __restrict__ polp, const float* __restrict__ polb,
    const float* __restrict__ vw, const float* __restrict__ vb,
    float* __restrict__ logits, float* __restrict__ values){
  __shared__ __align__(16) unsigned short al[64 * 136];
  int tid = threadIdx.x, w = tid >> 6, l = tid & 63, i = l & 15, u = l >> 4;
  long s0 = (long)blockIdx.x * 64;
  for (int idx = tid; idx < 64 * 16; idx += 256){
    int r = idx >> 4, q = idx & 15;
    *(v8s*)&al[r * 136 + q * 8] = *(const v8s*)&outsb[(s0 + r) * 128 + q * 8];
  }
  __syncthreads();
  v8s af[4][4];
  #pragma unroll
  for (int mt = 0; mt < 4; ++mt)
    #pragma unroll
    for (int ks = 0; ks < 4; ++ks)
      af[mt][ks] = *(const v8s*)&al[(mt * 16 + i) * 136 + ks * 32 + u * 8];
  const v8s* P = (const v8s*)polp;
  for (int nt = w; nt < 145; nt += 4){
    v4f acc[4];
    #pragma unroll
    for (int mt = 0; mt < 4; ++mt) acc[mt] = vzero();
    #pragma unroll
    for (int ks = 0; ks < 4; ++ks){
      v8s bb = P[(nt * 4 + ks) * 64 + l];
      #pragma unroll
      for (int mt = 0; mt < 4; ++mt) acc[mt] = MFMA(af[mt][ks], bb, acc[mt]);
    }
    int n = nt * 16 + i;
    if (n < 2305){
      float pbv = polb[n];
      #pragma unroll
      for (int mt = 0; mt < 4; ++mt)
        #pragma unroll
        for (int r = 0; r < 4; ++r)
          logits[(s0 + mt * 16 + u * 4 + r) * 2305 + n] = acc[mt][r] + pbv;
    }
  }
  // fused values: wave w covers rows w*16+i; lane group u handles cols g*32+u*8
  float vacc = 0.f;
  #pragma unroll
  for (int g = 0; g < 4; ++g){
    float4 vA = *(const float4*)&vw[g * 32 + u * 8];
    float4 vB = *(const float4*)&vw[g * 32 + u * 8 + 4];
    v8s xv = *(const v8s*)&al[(w * 16 + i) * 136 + g * 32 + u * 8];
    vacc += bf2f((unsigned short)xv[0]) * vA.x + bf2f((unsigned short)xv[1]) * vA.y
          + bf2f((unsigned short)xv[2]) * vA.z + bf2f((unsigned short)xv[3]) * vA.w
          + bf2f((unsigned short)xv[4]) * vB.x + bf2f((unsigned short)xv[5]) * vB.y
          + bf2f((unsigned short)xv[6]) * vB.z + bf2f((unsigned short)xv[7]) * vB.w;
  }
  vacc += __shfl_xor(vacc, 16);
  vacc += __shfl_xor(vacc, 32);
  if (u == 0) values[s0 + w * 16 + i] = vacc + vb[0];
}

// ---------------- launcher ----------------
extern "C" void kernel_launch(void* const* d_in, const int* in_sizes, int n_in,
                              void* d_out, int out_size, void* d_ws, size_t ws_size,
                              hipStream_t stream){
  (void)in_sizes; (void)n_in; (void)out_size; (void)ws_size;
  const float* obs = (const float*)d_in[0];
  const float* h0  = (const float*)d_in[1];
  const float* c0  = (const float*)d_in[2];
  const void*  dm  = d_in[3];
  const float* c1w = (const float*)d_in[4];  const float* c1b = (const float*)d_in[5];
  const float* c2w = (const float*)d_in[6];  const float* c2b = (const float*)d_in[7];
  const float* c3w = (const float*)d_in[8];  const float* c3b = (const float*)d_in[9];
  const float* fcw = (const float*)d_in[10]; const float* fcb = (const float*)d_in[11];
  const float* s1w = (const float*)d_in[12]; const float* s1b = (const float*)d_in[13];
  const float* s2w = (const float*)d_in[14]; const float* s2b = (const float*)d_in[15];
  const float* wih = (const float*)d_in[16]; const float* whh = (const float*)d_in[17];
  const float* bih = (const float*)d_in[18]; const float* bhh = (const float*)d_in[19];
  const float* pw  = (const float*)d_in[20]; const float* pb  = (const float*)d_in[21];
  const float* vw  = (const float*)d_in[22]; const float* vb  = (const float*)d_in[23];

  char* ws = (char*)d_ws;
  size_t off = 0;
  auto take = [&](size_t sz)->char*{
    char* p = ws + off; off = (off + sz + 255) & ~(size_t)255; return p;
  };
  unsigned short* emb    = (unsigned short*)take(32768UL * 192 * 2);
  unsigned short* outsb  = (unsigned short*)take(32768UL * 128 * 2);
  unsigned short* w1p    = (unsigned short*)take(1024UL * 2);
  unsigned short* w2p    = (unsigned short*)take(18432UL * 2);
  unsigned short* w3p    = (unsigned short*)take(36864UL * 2);
  unsigned short* fcp    = (unsigned short*)take(327680UL * 2);
  unsigned short* s1p    = (unsigned short*)take(30720UL * 2);
  unsigned short* s2p    = (unsigned short*)take(4096UL * 2);
  unsigned short* lsp    = (unsigned short*)take(163840UL * 2);
  unsigned short* pop    = (unsigned short*)take(296960UL * 2);
  float*          b512   = (float*)take(512UL * 4);
  unsigned int*   segs   = (unsigned int*)take(32768UL * 4);
  int4*           gtab   = (int4*)take(1280UL * 16);
  int*            meta   = (int*)take(256);

  float* outp   = (float*)d_out;
  float* logits = outp;
  float* values = outp + 75530240L;
  float* hf     = outp + 75563008L;
  float* cf     = outp + 75579392L;
  unsigned short* act3g = (unsigned short*)d_out;  // scratch overlay, dead before heads writes

  dim3 b256(256), b512t(512);
  pack_all<<<dim3(3438), b256, 0, stream>>>(c1w, c2w, c3w, fcw, s1w, s2w, wih, whh, pw,
                                            w1p, w2p, w3p, fcp, s1p, s2p, lsp, pop,
                                            dm, bih, bhh, b512, segs, gtab, meta);
  conv_kernel<<<dim3(512), b256, 0, stream>>>(obs, w1p, w2p, w3p, c1b, c2b, c3b, act3g);
  embed_kernel<<<dim3(1536), b256, 0, stream>>>(act3g, fcp, fcb, obs, s1p, s2p, s1b, s2b, emb);
  lstm_kernel<<<dim3(1280), b512t, 0, stream>>>(emb, lsp, b512, h0, c0, segs, gtab, meta,
                                                outsb, hf, cf);
  heads_kernel<<<dim3(512), b256, 0, stream>>>(outsb, pop, pb, vw, vb, logits, values);
}

// Round 15
// 1001.363 us; speedup vs baseline: 2.1551x; 2.1551x over previous
//
#include <hip/hip_runtime.h>

// CnnLstmPolicy: CNN(3 conv + fc) + scalar MLP -> LSTM (done-mask segmented) -> heads
// All GEMM-shaped compute via v_mfma_f32_16x16x32_bf16 (bf16 operands, f32 accum).
// Conv kernel: the R13-measured 546us configuration, VERBATIM: 256 threads, (256,2),
// 74.5KB LDS (2 blocks/CU), no im2col, padded ACT1/ACT2, phase-local w2f/w3q weight
// reloads, 2 barriers/sample, conv3 straight to global. Register law (measured
// R6/R11/R12/R14): total per-wave budget at 2 waves/SIMD is 256 (VGPR+acc, unified);
// this kernel sits just under it -- ANY register addition (persistent w2f, hoisted
// addressing) or forced-occupancy declaration spills to scratch (FETCH 76MB -> >1GB).
// Tail: pack_all absorbs segprep+bias; embed_kernel = fc+mlp heterogeneous launch.

typedef __attribute__((ext_vector_type(8))) short v8s;        // 8 x bf16 (4 VGPR)
typedef __attribute__((ext_vector_type(4))) float v4f;        // mfma accumulator
typedef __attribute__((ext_vector_type(4))) unsigned int v4u;

#define DEV static __device__ __forceinline__

DEV unsigned int cvtpk(float lo, float hi){
  unsigned int d;
  asm("v_cvt_pk_bf16_f32 %0, %1, %2" : "=v"(d) : "v"(lo), "v"(hi));  // RNE, S0->low
  return d;
}
DEV unsigned short f2bf(float x){ return (unsigned short)(cvtpk(x, x) & 0xffffu); }
DEV float bf2f(unsigned short h){ return __uint_as_float(((unsigned int)h) << 16); }
DEV unsigned int pkbf(float a, float b){ return cvtpk(a, b); }
DEV v4f MFMA(v8s a, v8s b, v4f c){ return __builtin_amdgcn_mfma_f32_16x16x32_bf16(a, b, c, 0, 0, 0); }
DEV v4f vzero(){ v4f z = {0.f, 0.f, 0.f, 0.f}; return z; }
DEV float relu(float x){ return x > 0.f ? x : 0.f; }
DEV float sigm(float x){ return 1.0f / (1.0f + __expf(-x)); }
DEV float tanhfast(float x){
  x = fminf(15.0f, fmaxf(-15.0f, x));
  float e = __expf(2.0f * x);
  return (e - 1.0f) / (e + 1.0f);
}
DEV uint2 pack4(v4f a, float4 b){  // (a+bias) -> relu -> 4x bf16 packed (2 cvt_pk)
  return make_uint2(cvtpk(relu(a[0]+b.x), relu(a[1]+b.y)),
                    cvtpk(relu(a[2]+b.z), relu(a[3]+b.w)));
}
union U8S { v4u u4; v8s s8; };

// ---------------- weight packing + segprep + bias (single launch) ----------------
// dst[(nt*KS+ks)*512 + lane*8 + e] = W[n][k], n = nt*16 + (lane&15), k = ks*32 + (lane>>4)*8 + e
// mode 0: direct  src[n*K + k]
// mode 1: conv    k = p9*CI + ci -> src[(n*CI+ci)*9 + p9]
// mode 2: fc      k = pos*64+ci  -> src[n*2560 + ci*40 + pos]
// mode 3: lstm    k<192: w_ih[n*192+k], else w_hh[n*128+k-192]
// mode 4: conv1   k = dy*8 + dx*2 + ci -> src[(n*2+ci)*9 + dy*3+dx]  (dx==3 / k>=K zero)
// block 3436: segprep (done-mask -> equal-length segment groups); block 3437: bias add
__global__ __launch_bounds__(256) void pack_all(
    const float* __restrict__ c1w, const float* __restrict__ c2w,
    const float* __restrict__ c3w, const float* __restrict__ fcw,
    const float* __restrict__ s1w, const float* __restrict__ s2w,
    const float* __restrict__ wih, const float* __restrict__ whh,
    const float* __restrict__ pw,
    unsigned short* __restrict__ w1p, unsigned short* __restrict__ w2p,
    unsigned short* __restrict__ w3p, unsigned short* __restrict__ fcp,
    unsigned short* __restrict__ s1p, unsigned short* __restrict__ s2p,
    unsigned short* __restrict__ lsp, unsigned short* __restrict__ pop,
    const void* __restrict__ dmask, const float* __restrict__ bih,
    const float* __restrict__ bhh, float* __restrict__ bias512,
    unsigned int* __restrict__ segs, int4* __restrict__ gtab, int* __restrict__ meta){
  __shared__ int sp[772];   // segprep scratch: cnt[257], off[257], place[257], notInt
  int b = blockIdx.x;
  int tid = threadIdx.x;
  if (b == 3437){
    bias512[tid] = bih[tid] + bhh[tid];
    bias512[tid + 256] = bih[tid + 256] + bhh[tid + 256];
    return;
  }
  if (b == 3436){
    int* cnt = sp; int* off = sp + 257; int* place = sp + 514;
    for (int idx = tid; idx < 257; idx += 256){ cnt[idx] = 0; place[idx] = 0; }
    if (tid == 0) sp[771] = 0;
    __syncthreads();
    const unsigned char* p8 = (const unsigned char*)dmask;
    int nz = 0;
    for (int idx = tid; idx < 2048; idx += 256)
      if (p8[idx * 4 + 1] | p8[idx * 4 + 2] | p8[idx * 4 + 3]) nz = 1;
    if (nz) sp[771] = 1;
    __syncthreads();
    bool m32 = (sp[771] == 0);
    const int* p32 = (const int*)dmask;
    if (tid < 128){
      int bb = tid, ts = 0;
      for (int t = 0; t < 256; ++t){
        bool d = (t == 255) ? true : (m32 ? (p32[t * 128 + bb] != 0) : (p8[t * 128 + bb] != 0));
        if (d){ atomicAdd(&cnt[t - ts + 1], 1); ts = t + 1; }
      }
    }
    __syncthreads();
    if (tid == 0){
      int acc = 0;
      for (int len = 1; len <= 256; ++len){ off[len] = acc; acc += cnt[len]; }
      int G = 0;
      for (int len = 1; len <= 256; ++len){
        int c = cnt[len], g = 0;
        while (c > 0){
          int take = c < 32 ? c : 32;
          gtab[G] = make_int4(len, off[len] + g * 32, take, 0);
          ++G; c -= 32; ++g;
        }
      }
      meta[0] = G;
    }
    __syncthreads();
    if (tid < 128){
      int bb = tid, ts = 0;
      for (int t = 0; t < 256; ++t){
        bool d = (t == 255) ? true : (m32 ? (p32[t * 128 + bb] != 0) : (p8[t * 128 + bb] != 0));
        if (d){
          int len = t - ts + 1;
          int slot = off[len] + atomicAdd(&place[len], 1);
          segs[slot] = (unsigned int)(bb | (ts << 8));
          ts = t + 1;
        }
      }
    }
    return;
  }
  const float *src, *src2 = nullptr; unsigned short* dst;
  int N, K, KS, CI, mode, rel;
  if      (b < 4)   { src=c1w; dst=w1p; N=32;  K=24;  KS=1;  CI=2;  mode=4; rel=b; }
  else if (b < 76)  { src=c2w; dst=w2p; N=64;  K=288; KS=9;  CI=32; mode=1; rel=b-4; }
  else if (b < 220) { src=c3w; dst=w3p; N=64;  K=576; KS=18; CI=64; mode=1; rel=b-76; }
  else if (b < 1500){ src=fcw; dst=fcp; N=128; K=2560;KS=80; CI=0;  mode=2; rel=b-220; }
  else if (b < 1620){ src=s1w; dst=s1p; N=64;  K=452; KS=15; CI=0;  mode=0; rel=b-1500; }
  else if (b < 1636){ src=s2w; dst=s2p; N=64;  K=64;  KS=2;  CI=0;  mode=0; rel=b-1620; }
  else if (b < 2276){ src=wih; src2=whh; dst=lsp; N=512; K=320; KS=10; CI=0; mode=3; rel=b-1636; }
  else              { src=pw;  dst=pop; N=2305;K=128; KS=4;  CI=0;  mode=0; rel=b-2276; }
  int idx = rel * 256 + tid;
  int e  = idx & 7;
  int l  = (idx >> 3) & 63;
  int fs = idx >> 9;
  int ks = fs % KS;
  int nt = fs / KS;
  int n = nt * 16 + (l & 15);
  int k = ks * 32 + (l >> 4) * 8 + e;
  float v = 0.f;
  if (n < N && k < K){
    if (mode == 0)      v = src[n * K + k];
    else if (mode == 1){ int p9 = k / CI, ci = k - p9 * CI; v = src[(n * CI + ci) * 9 + p9]; }
    else if (mode == 2){ int pos = k >> 6, ci = k & 63;     v = src[n * 2560 + ci * 40 + pos]; }
    else if (mode == 3) v = (k < 192) ? src[n * 192 + k] : src2[n * 128 + (k - 192)];
    else { int dy = k >> 3, r = k & 7, dx = r >> 1, ci = r & 1;
           if (dx < 3) v = src[(n * 2 + ci) * 9 + dy * 3 + dx]; }
  }
  dst[idx] = f2bf(v);
}

// ---------------- fused conv1/conv2/conv3 per sample (R13 config, no im2col) ----------------
// LDS map (all zeroed once; halos never rewritten):
//  ACT1: [34 rows][20 cols][32ch] bf16  = 43520 B, swizzle ^(((p>>1)&7)<<4)
//  ACT2: [18 rows][11 cols][64ch] bf16  = 25344 B, swizzle ^(((p>>1)&7)<<4)
//  GRID: 2 x [35 rows][20 cols] u32 (ch0 lo, ch1 hi) = 2 x 2816 B, linear
#define ACT1o 0
#define ACT2o 43520
#define GRIDo 68864
#define SWZ(p) ((((p) >> 1) & 7) << 4)

__global__ __launch_bounds__(256, 2) void conv_kernel(const float* __restrict__ obs,
    const unsigned short* __restrict__ w1p, const unsigned short* __restrict__ w2p,
    const unsigned short* __restrict__ w3p,
    const float* __restrict__ b1v, const float* __restrict__ b2v, const float* __restrict__ b3v,
    unsigned short* __restrict__ act3g){
  __shared__ __align__(16) char lds[74496];
  int tid = threadIdx.x, w = tid >> 6, l = tid & 63, i = l & 15, u = l >> 4;
  int nh = w & 1, mh = w >> 1;
  const v8s* W1 = (const v8s*)w1p;
  const v8s* W2 = (const v8s*)w2p;
  const v8s* W3 = (const v8s*)w3p;
  v8s w1f0 = W1[l], w1f1 = W1[64 + l];              // persistent conv1 weights
  float4 bc1a = *(const float4*)&b1v[u * 4];
  float4 bc1b = *(const float4*)&b1v[16 + u * 4];
  float4 bc2a = *(const float4*)&b2v[nh * 32 + u * 4];
  float4 bc2b = *(const float4*)&b2v[nh * 32 + 16 + u * 4];
  float4 bc3a = *(const float4*)&b3v[nh * 32 + u * 4];
  float4 bc3b = *(const float4*)&b3v[nh * 32 + 16 + u * 4];
  // zero ALL of LDS once (covers halos + grid pad rows)
  for (int idx = tid; idx < 18624; idx += 256) *(unsigned int*)(lds + idx * 4) = 0u;
  // staging offsets: thread tid<144 owns pixels 4tid..4tid+3 -> padded [r+1][c+1]
  int soff[4];
  #pragma unroll
  for (int j = 0; j < 4; ++j){
    int p = tid * 4 + j, r = p / 18, c = p - r * 18;
    soff[j] = ((r + 1) * 20 + (c + 1)) * 4;
  }
  __syncthreads();
  long sbase = (long)blockIdx.x * 64;
  if (tid < 144){
    const float4* gp = (const float4*)(obs + sbase * 1604 + 452);
    float4 a = gp[tid], b = gp[tid + 144];
    *(unsigned int*)(lds + GRIDo + soff[0]) = pkbf(a.x, b.x);
    *(unsigned int*)(lds + GRIDo + soff[1]) = pkbf(a.y, b.y);
    *(unsigned int*)(lds + GRIDo + soff[2]) = pkbf(a.z, b.z);
    *(unsigned int*)(lds + GRIDo + soff[3]) = pkbf(a.w, b.w);
  }
  __syncthreads();

  // conv3 per-wave geometry (it-invariant): one 16-pos tile per wave pair + tail on mh==0
  int pos3_0 = (mh ? 1 : 0) * 16 + i;                 // slot 0 pos (always < 32)
  int pos3_1r = 32 + i;                               // slot 1 raw pos (mh==0 only)
  int pos3_1 = pos3_1r > 39 ? 39 : pos3_1r;
  int oh30 = pos3_0 / 5, ow30 = pos3_0 - oh30 * 5;
  int oh31 = pos3_1 / 5, ow31 = pos3_1 - oh31 * 5;
  int pr3_0 = (2 * oh30) * 11 + 2 * ow30;
  int pr3_1 = (2 * oh31) * 11 + 2 * ow31;

  for (int it = 0; it < 64; ++it){
    long s = sbase + it;
    int gbo = GRIDo + (it & 1) * 2816;
    // conv2 weight loads (phase-local; LICM blocked)
    int z2; asm("s_mov_b32 %0, 0" : "=s"(z2) : "s"(it));
    v8s w2f[2][9];
    #pragma unroll
    for (int jj = 0; jj < 2; ++jj)
      #pragma unroll
      for (int t = 0; t < 9; ++t) w2f[jj][t] = W2[((nh * 2 + jj) * 9 + t) * 64 + l + z2];
    // prefetch next sample's grid
    float4 pa, pb; bool pf = (it < 63) && (tid < 144);
    if (pf){
      const float4* gp = (const float4*)(obs + (s + 1) * 1604 + 452);
      pa = gp[tid]; pb = gp[tid + 144];
    }
    // ---- conv1: fragments straight from padded grid; 9 pos-tiles per wave ----
    #pragma unroll
    for (int k = 0; k < 9; ++k){
      int ntl = w + 4 * k;
      int pos = ntl * 16 + i;
      int oh = pos / 18, ow = pos - oh * 18;
      int glin = gbo + ((oh + u) * 20 + ow) * 4;      // row oh+u, cols ow..ow+3
      U8S gv;
      gv.u4.x = *(const unsigned int*)(lds + glin);
      gv.u4.y = *(const unsigned int*)(lds + glin + 4);
      gv.u4.z = *(const unsigned int*)(lds + glin + 8);
      gv.u4.w = *(const unsigned int*)(lds + glin + 12);
      v4f a0 = MFMA(w1f0, gv.s8, vzero());
      v4f a1 = MFMA(w1f1, gv.s8, vzero());
      int p1 = (oh + 1) * 20 + (ow + 1);
      int sA = SWZ(p1);
      *(uint2*)(lds + ACT1o + ((p1 * 64 + u * 8) ^ sA))      = pack4(a0, bc1a);
      *(uint2*)(lds + ACT1o + ((p1 * 64 + 32 + u * 8) ^ sA)) = pack4(a1, bc1b);
    }
    __syncthreads();   // B: ACT1 visible; grid reads done
    // ---- conv2: 16x9 out, 64 ch; wave (nh,mh): ch-pair nh, pos parity mh ----
    for (int ntl = mh; ntl < 9; ntl += 2){
      int pos2 = ntl * 16 + i;
      int oh = pos2 / 9, ow = pos2 - oh * 9;
      int pr0 = (2 * oh) * 20 + 2 * ow;
      v4f a0 = vzero(), a1 = vzero();
      #pragma unroll
      for (int dy = 0; dy < 3; ++dy)
        #pragma unroll
        for (int dx = 0; dx < 3; ++dx){
          int p = pr0 + dy * 20 + dx;
          int byte = (p * 64 + u * 16) ^ SWZ(p);
          v8s bf = *(const v8s*)(lds + ACT1o + byte);
          a0 = MFMA(w2f[0][dy * 3 + dx], bf, a0);
          a1 = MFMA(w2f[1][dy * 3 + dx], bf, a1);
        }
      int p2 = (oh + 1) * 11 + (ow + 1);
      int sB = SWZ(p2);
      *(uint2*)(lds + ACT2o + ((p2 * 128 + nh * 64 + u * 8) ^ sB))      = pack4(a0, bc2a);
      *(uint2*)(lds + ACT2o + ((p2 * 128 + nh * 64 + 32 + u * 8) ^ sB)) = pack4(a1, bc2b);
    }
    // stage next sample's grid into the other buffer (visible after barrier C)
    if (pf){
      int gbn = GRIDo + ((it + 1) & 1) * 2816;
      *(unsigned int*)(lds + gbn + soff[0]) = pkbf(pa.x, pb.x);
      *(unsigned int*)(lds + gbn + soff[1]) = pkbf(pa.y, pb.y);
      *(unsigned int*)(lds + gbn + soff[2]) = pkbf(pa.z, pb.z);
      *(unsigned int*)(lds + gbn + soff[3]) = pkbf(pa.w, pb.w);
    }
    __syncthreads();   // C: ACT2 + next grid visible
    // ---- conv3: ch-pair nh x pos-split mh (mh0: tiles 0,2; mh1: tile 1); K in 2 chunks ----
    {
      int z3; asm("s_mov_b32 %0, 0" : "=s"(z3) : "s"(it));
      v4f c300 = vzero(), c301 = vzero(), c310 = vzero(), c311 = vzero();
      #pragma unroll
      for (int ksh = 0; ksh < 2; ++ksh){
        const int t0 = ksh * 5, tc = ksh ? 4 : 5;
        v8s w3q[2][5][2];
        #pragma unroll
        for (int j = 0; j < 2; ++j)
          #pragma unroll
          for (int tt = 0; tt < 5; ++tt){
            if (tt < tc){
              #pragma unroll
              for (int h = 0; h < 2; ++h)
                w3q[j][tt][h] = W3[((2 * nh + j) * 18 + 2 * (t0 + tt) + h) * 64 + l + z3];
            }
          }
        #pragma unroll
        for (int tt = 0; tt < 5; ++tt){
          if (tt < tc){
            int tap = t0 + tt, dy = tap / 3, dx = tap - dy * 3;
            int dpp = dy * 11 + dx;
            #pragma unroll
            for (int h = 0; h < 2; ++h){
              {
                int p = pr3_0 + dpp;
                int byte = (p * 128 + h * 64 + u * 16) ^ SWZ(p);
                v8s bf = *(const v8s*)(lds + ACT2o + byte);
                c300 = MFMA(w3q[0][tt][h], bf, c300);
                c301 = MFMA(w3q[1][tt][h], bf, c301);
              }
              if (mh == 0){
                int p = pr3_1 + dpp;
                int byte = (p * 128 + h * 64 + u * 16) ^ SWZ(p);
                v8s bf = *(const v8s*)(lds + ACT2o + byte);
                c310 = MFMA(w3q[0][tt][h], bf, c310);
                c311 = MFMA(w3q[1][tt][h], bf, c311);
              }
            }
          }
        }
      }
      unsigned short* dg = act3g + s * 2560;
      *(uint2*)(dg + pos3_0 * 64 + nh * 32 + u * 4)      = pack4(c300, bc3a);
      *(uint2*)(dg + pos3_0 * 64 + nh * 32 + 16 + u * 4) = pack4(c301, bc3b);
      if (mh == 0 && pos3_1r < 40){
        *(uint2*)(dg + pos3_1r * 64 + nh * 32 + u * 4)      = pack4(c310, bc3a);
        *(uint2*)(dg + pos3_1r * 64 + nh * 32 + 16 + u * 4) = pack4(c311, bc3b);
      }
    }
    // no trailing barrier: conv3's ACT2 reads are protected by next iteration's barrier B
  }
}

// ---------------- embed: fc (blocks 0..511) + scalar MLP (blocks 512..1535) ----------------
__global__ __launch_bounds__(256) void embed_kernel(
    const unsigned short* __restrict__ act3g, const unsigned short* __restrict__ fcp,
    const float* __restrict__ fcb,
    const float* __restrict__ obs, const unsigned short* __restrict__ s1p,
    const unsigned short* __restrict__ s2p,
    const float* __restrict__ s1b, const float* __restrict__ s2b,
    unsigned short* __restrict__ emb){
  __shared__ __align__(16) unsigned short shb[17920];
  int bid = blockIdx.x;
  int tid = threadIdx.x, w = tid >> 6, l = tid & 63, i = l & 15, u = l >> 4;
  if (bid < 512){
    // ---- fc: act3(2560) -> 128, relu -> emb[:,0:128] ----
    unsigned short* al = shb;                        // [64 rows][264]
    long s0 = (long)bid * 64;
    v4f acc[4][2];
    #pragma unroll
    for (int mt = 0; mt < 4; ++mt){ acc[mt][0] = vzero(); acc[mt][1] = vzero(); }
    const v8s* F = (const v8s*)fcp;
    for (int kc = 0; kc < 10; ++kc){
      __syncthreads();
      for (int idx = tid; idx < 64 * 32; idx += 256){
        int r = idx >> 5, q = idx & 31;
        *(v8s*)&al[r * 264 + q * 8] = *(const v8s*)&act3g[(s0 + r) * 2560 + kc * 256 + q * 8];
      }
      __syncthreads();
      #pragma unroll
      for (int ksl = 0; ksl < 8; ++ksl){
        v8s b0 = F[((w * 2 + 0) * 80 + kc * 8 + ksl) * 64 + l];
        v8s b1 = F[((w * 2 + 1) * 80 + kc * 8 + ksl) * 64 + l];
        #pragma unroll
        for (int mt = 0; mt < 4; ++mt){
          v8s aa = *(const v8s*)&al[(mt * 16 + i) * 264 + ksl * 32 + u * 8];
          acc[mt][0] = MFMA(aa, b0, acc[mt][0]);
          acc[mt][1] = MFMA(aa, b1, acc[mt][1]);
        }
      }
    }
    float fb0 = fcb[(w * 2) * 16 + i], fb1 = fcb[(w * 2 + 1) * 16 + i];
    #pragma unroll
    for (int mt = 0; mt < 4; ++mt)
      #pragma unroll
      for (int r = 0; r < 4; ++r){
        float v0 = relu(acc[mt][0][r] + fb0);
        float v1 = relu(acc[mt][1][r] + fb1);
        emb[(s0 + mt * 16 + u * 4 + r) * 192 + (w * 2) * 16 + i] = f2bf(v0);
        emb[(s0 + mt * 16 + u * 4 + r) * 192 + (w * 2 + 1) * 16 + i] = f2bf(v1);
      }
  } else {
    // ---- scalar MLP: obs[:,:452] -> 64 -> 64 -> emb[:,128:192] ----
    unsigned short* xl = shb;                        // [32 rows][488]
    unsigned short* h1 = shb + 15616;                // [32 rows][72]
    long s0 = (long)(bid - 512) * 32;
    for (int idx = tid; idx < 32 * 113; idx += 256){
      int r = idx / 113, q = idx - r * 113;
      float4 v = *(const float4*)&obs[(s0 + r) * 1604 + q * 4];
      *(uint2*)&xl[r * 488 + q * 4] = make_uint2(pkbf(v.x, v.y), pkbf(v.z, v.w));
    }
    for (int idx = tid; idx < 32 * 28; idx += 256){   // zero pad cols 452..479
      int r = idx / 28, k = 452 + (idx - r * 28);
      xl[r * 488 + k] = 0;
    }
    __syncthreads();
    v4f acc0 = vzero(), acc1 = vzero();
    const v8s* F1 = (const v8s*)s1p;
    #pragma unroll
    for (int ks = 0; ks < 15; ++ks){
      v8s bb = F1[(w * 15 + ks) * 64 + l];
      v8s aa0 = *(const v8s*)&xl[(0 * 16 + i) * 488 + ks * 32 + u * 8];
      v8s aa1 = *(const v8s*)&xl[(1 * 16 + i) * 488 + ks * 32 + u * 8];
      acc0 = MFMA(aa0, bb, acc0);
      acc1 = MFMA(aa1, bb, acc1);
    }
    float b1 = s1b[w * 16 + i];
    #pragma unroll
    for (int r = 0; r < 4; ++r){
      float v0 = relu(acc0[r] + b1);
      float v1 = relu(acc1[r] + b1);
      h1[(u * 4 + r) * 72 + w * 16 + i] = f2bf(v0);
      h1[(16 + u * 4 + r) * 72 + w * 16 + i] = f2bf(v1);
    }
    __syncthreads();
    v4f a20 = vzero(), a21 = vzero();
    const v8s* F2 = (const v8s*)s2p;
    #pragma unroll
    for (int ks = 0; ks < 2; ++ks){
      v8s bb = F2[(w * 2 + ks) * 64 + l];
      v8s aa0 = *(const v8s*)&h1[(0 * 16 + i) * 72 + ks * 32 + u * 8];
      v8s aa1 = *(const v8s*)&h1[(1 * 16 + i) * 72 + ks * 32 + u * 8];
      a20 = MFMA(aa0, bb, a20);
      a21 = MFMA(aa1, bb, a21);
    }
    float b2 = s2b[w * 16 + i];
    #pragma unroll
    for (int r = 0; r < 4; ++r){
      float v0 = relu(a20[r] + b2);
      float v1 = relu(a21[r] + b2);
      emb[(s0 + u * 4 + r) * 192 + 128 + w * 16 + i] = f2bf(v0);
      emb[(s0 + 16 + u * 4 + r) * 192 + 128 + w * 16 + i] = f2bf(v1);
    }
  }
}

// ---------------- LSTM over segment groups: M=32 segs, N=512 gates, K=320 ----------------
__global__ __launch_bounds__(512) void lstm_kernel(
    const unsigned short* __restrict__ emb, const unsigned short* __restrict__ lstmp,
    const float* __restrict__ bias512,
    const float* __restrict__ h0, const float* __restrict__ c0,
    const unsigned int* __restrict__ segs, const int4* __restrict__ gtab,
    const int* __restrict__ meta,
    unsigned short* __restrict__ outsb, float* __restrict__ hf, float* __restrict__ cf){
  int grp = blockIdx.x;
  if (grp >= meta[0]) return;
  int4 gd = gtab[grp];
  int len = gd.x, base = gd.y, nseg = gd.z;
  __shared__ __align__(16) unsigned short hbuf[2][32 * 136];
  __shared__ int sb[32], st[32];
  int tid = threadIdx.x, w = tid >> 6, l = tid & 63, i = l & 15, u = l >> 4;
  if (tid < 32){
    unsigned int sv = segs[base + (tid < nseg ? tid : 0)];
    sb[tid] = (int)(sv & 127u);
    st[tid] = (int)((sv >> 8) & 255u);
  }
  __syncthreads();
  int j = w * 16 + i;
  float cst[2][4];
  #pragma unroll
  for (int mt = 0; mt < 2; ++mt)
    #pragma unroll
    for (int r = 0; r < 4; ++r){
      int slot = mt * 16 + u * 4 + r;
      float cv = 0.f, hv = 0.f;
      if (st[slot] == 0){ cv = c0[sb[slot] * 128 + j]; hv = h0[sb[slot] * 128 + j]; }
      cst[mt][r] = cv;
      hbuf[0][slot * 136 + j] = f2bf(hv);
    }
  float bi = bias512[j], bff = bias512[128 + j], bg = bias512[256 + j], bo = bias512[384 + j];
  int bA0 = sb[i], tA0 = st[i];
  int bA1 = sb[16 + i], tA1 = st[16 + i];
  __syncthreads();
  const v8s* LP = (const v8s*)lstmp;
  for (int step = 0; step < len; ++step){
    int pb = step & 1;
    v4f gi0 = vzero(), gi1 = vzero(), gf0 = vzero(), gf1 = vzero();
    v4f gg0 = vzero(), gg1 = vzero(), go0 = vzero(), go1 = vzero();
    #pragma unroll
    for (int ks = 0; ks < 10; ++ks){
      v8s a0, a1;
      if (ks < 6){
        a0 = *(const v8s*)&emb[((long)(tA0 + step) * 128 + bA0) * 192 + ks * 32 + u * 8];
        a1 = *(const v8s*)&emb[((long)(tA1 + step) * 128 + bA1) * 192 + ks * 32 + u * 8];
      } else {
        int koff = (ks - 6) * 32 + u * 8;
        a0 = *(const v8s*)&hbuf[pb][i * 136 + koff];
        a1 = *(const v8s*)&hbuf[pb][(16 + i) * 136 + koff];
      }
      v8s b_i = LP[((w) * 10 + ks) * 64 + l];
      v8s b_f = LP[((w + 8) * 10 + ks) * 64 + l];
      v8s b_g = LP[((w + 16) * 10 + ks) * 64 + l];
      v8s b_o = LP[((w + 24) * 10 + ks) * 64 + l];
      gi0 = MFMA(a0, b_i, gi0); gi1 = MFMA(a1, b_i, gi1);
      gf0 = MFMA(a0, b_f, gf0); gf1 = MFMA(a1, b_f, gf1);
      gg0 = MFMA(a0, b_g, gg0); gg1 = MFMA(a1, b_g, gg1);
      go0 = MFMA(a0, b_o, go0); go1 = MFMA(a1, b_o, go1);
    }
    #pragma unroll
    for (int mt = 0; mt < 2; ++mt)
      #pragma unroll
      for (int r = 0; r < 4; ++r){
        int slot = mt * 16 + u * 4 + r;
        float giv = mt ? gi1[r] : gi0[r];
        float gfv = mt ? gf1[r] : gf0[r];
        float ggv = mt ? gg1[r] : gg0[r];
        float gov = mt ? go1[r] : go0[r];
        float iv = sigm(giv + bi);
        float fv = sigm(gfv + bff);
        float gv = tanhfast(ggv + bg);
        float ov = sigm(gov + bo);
        float cv = fv * cst[mt][r] + iv * gv;
        cst[mt][r] = cv;
        float hv = ov * tanhfast(cv);
        unsigned short hb = f2bf(hv);
        hbuf[pb ^ 1][slot * 136 + j] = hb;
        if (slot < nseg){
          outsb[((long)(st[slot] + step) * 128 + sb[slot]) * 128 + j] = hb;
          if (st[slot] + len == 256 && step == len - 1){
            hf[sb[slot] * 128 + j] = hv;
            cf[sb[slot] * 128 + j] = cv;
          }
        }
      }
    __syncthreads();
  }
}

// ---------------- heads: logits = outs @ pol_w.T + pol_b; values fused ----------------
__global__ __launch_bounds__(256) void heads_kernel(const unsigned short* __restrict__ outsb,
    const unsigned short* __restrict__ polp, const float* __restrict__ polb,
    const float* __restrict__ vw, const float* __restrict__ vb,
    float* __restrict__ logits, float* __restrict__ values){
  __shared__ __align__(16) unsigned short al[64 * 136];
  int tid = threadIdx.x, w = tid >> 6, l = tid & 63, i = l & 15, u = l >> 4;
  long s0 = (long)blockIdx.x * 64;
  for (int idx = tid; idx < 64 * 16; idx += 256){
    int r = idx >> 4, q = idx & 15;
    *(v8s*)&al[r * 136 + q * 8] = *(const v8s*)&outsb[(s0 + r) * 128 + q * 8];
  }
  __syncthreads();
  v8s af[4][4];
  #pragma unroll
  for (int mt = 0; mt < 4; ++mt)
    #pragma unroll
    for (int ks = 0; ks < 4; ++ks)
      af[mt][ks] = *(const v8s*)&al[(mt * 16 + i) * 136 + ks * 32 + u * 8];
  const v8s* P = (const v8s*)polp;
  for (int nt = w; nt < 145; nt += 4){
    v4f acc[4];
    #pragma unroll
    for (int mt = 0; mt < 4; ++mt) acc[mt] = vzero();
    #pragma unroll
    for (int ks = 0; ks < 4; ++ks){
      v8s bb = P[(nt * 4 + ks) * 64 + l];
      #pragma unroll
      for (int mt = 0; mt < 4; ++mt) acc[mt] = MFMA(af[mt][ks], bb, acc[mt]);
    }
    int n = nt * 16 + i;
    if (n < 2305){
      float pbv = polb[n];
      #pragma unroll
      for (int mt = 0; mt < 4; ++mt)
        #pragma unroll
        for (int r = 0; r < 4; ++r)
          logits[(s0 + mt * 16 + u * 4 + r) * 2305 + n] = acc[mt][r] + pbv;
    }
  }
  // fused values: wave w covers rows w*16+i; lane group u handles cols g*32+u*8
  float vacc = 0.f;
  #pragma unroll
  for (int g = 0; g < 4; ++g){
    float4 vA = *(const float4*)&vw[g * 32 + u * 8];
    float4 vB = *(const float4*)&vw[g * 32 + u * 8 + 4];
    v8s xv = *(const v8s*)&al[(w * 16 + i) * 136 + g * 32 + u * 8];
    vacc += bf2f((unsigned short)xv[0]) * vA.x + bf2f((unsigned short)xv[1]) * vA.y
          + bf2f((unsigned short)xv[2]) * vA.z + bf2f((unsigned short)xv[3]) * vA.w
          + bf2f((unsigned short)xv[4]) * vB.x + bf2f((unsigned short)xv[5]) * vB.y
          + bf2f((unsigned short)xv[6]) * vB.z + bf2f((unsigned short)xv[7]) * vB.w;
  }
  vacc += __shfl_xor(vacc, 16);
  vacc += __shfl_xor(vacc, 32);
  if (u == 0) values[s0 + w * 16 + i] = vacc + vb[0];
}

// ---------------- launcher ----------------
extern "C" void kernel_launch(void* const* d_in, const int* in_sizes, int n_in,
                              void* d_out, int out_size, void* d_ws, size_t ws_size,
                              hipStream_t stream){
  (void)in_sizes; (void)n_in; (void)out_size; (void)ws_size;
  const float* obs = (const float*)d_in[0];
  const float* h0  = (const float*)d_in[1];
  const float* c0  = (const float*)d_in[2];
  const void*  dm  = d_in[3];
  const float* c1w = (const float*)d_in[4];  const float* c1b = (const float*)d_in[5];
  const float* c2w = (const float*)d_in[6];  const float* c2b = (const float*)d_in[7];
  const float* c3w = (const float*)d_in[8];  const float* c3b = (const float*)d_in[9];
  const float* fcw = (const float*)d_in[10]; const float* fcb = (const float*)d_in[11];
  const float* s1w = (const float*)d_in[12]; const float* s1b = (const float*)d_in[13];
  const float* s2w = (const float*)d_in[14]; const float* s2b = (const float*)d_in[15];
  const float* wih = (const float*)d_in[16]; const float* whh = (const float*)d_in[17];
  const float* bih = (const float*)d_in[18]; const float* bhh = (const float*)d_in[19];
  const float* pw  = (const float*)d_in[20]; const float* pb  = (const float*)d_in[21];
  const float* vw  = (const float*)d_in[22]; const float* vb  = (const float*)d_in[23];

  char* ws = (char*)d_ws;
  size_t off = 0;
  auto take = [&](size_t sz)->char*{
    char* p = ws + off; off = (off + sz + 255) & ~(size_t)255; return p;
  };
  unsigned short* emb    = (unsigned short*)take(32768UL * 192 * 2);
  unsigned short* outsb  = (unsigned short*)take(32768UL * 128 * 2);
  unsigned short* w1p    = (unsigned short*)take(1024UL * 2);
  unsigned short* w2p    = (unsigned short*)take(18432UL * 2);
  unsigned short* w3p    = (unsigned short*)take(36864UL * 2);
  unsigned short* fcp    = (unsigned short*)take(327680UL * 2);
  unsigned short* s1p    = (unsigned short*)take(30720UL * 2);
  unsigned short* s2p    = (unsigned short*)take(4096UL * 2);
  unsigned short* lsp    = (unsigned short*)take(163840UL * 2);
  unsigned short* pop    = (unsigned short*)take(296960UL * 2);
  float*          b512   = (float*)take(512UL * 4);
  unsigned int*   segs   = (unsigned int*)take(32768UL * 4);
  int4*           gtab   = (int4*)take(1280UL * 16);
  int*            meta   = (int*)take(256);

  float* outp   = (float*)d_out;
  float* logits = outp;
  float* values = outp + 75530240L;
  float* hf     = outp + 75563008L;
  float* cf     = outp + 75579392L;
  unsigned short* act3g = (unsigned short*)d_out;  // scratch overlay, dead before heads writes

  dim3 b256(256), b512t(512);
  pack_all<<<dim3(3438), b256, 0, stream>>>(c1w, c2w, c3w, fcw, s1w, s2w, wih, whh, pw,
                                            w1p, w2p, w3p, fcp, s1p, s2p, lsp, pop,
                                            dm, bih, bhh, b512, segs, gtab, meta);
  conv_kernel<<<dim3(512), b256, 0, stream>>>(obs, w1p, w2p, w3p, c1b, c2b, c3b, act3g);
  embed_kernel<<<dim3(1536), b256, 0, stream>>>(act3g, fcp, fcb, obs, s1p, s2p, s1b, s2b, emb);
  lstm_kernel<<<dim3(1280), b512t, 0, stream>>>(emb, lsp, b512, h0, c0, segs, gtab, meta,
                                                outsb, hf, cf);
  heads_kernel<<<dim3(512), b256, 0, stream>>>(outsb, pop, pb, vw, vb, logits, values);
}

// Round 16
// 994.083 us; speedup vs baseline: 2.1709x; 1.0073x over previous
//
#include <hip/hip_runtime.h>

// CnnLstmPolicy: CNN(3 conv + fc) + scalar MLP -> LSTM (done-mask segmented) -> heads
// All GEMM-shaped compute via v_mfma_f32_16x16x32_bf16 (bf16 operands, f32 accum).
// Conv kernel: the R13-measured 546us configuration, FROZEN: 256 threads, (256,2),
// 74.5KB LDS (2 blocks/CU), no im2col, padded ACT1/ACT2, phase-local w2f/w3q weight
// reloads, 2 barriers/sample, conv3 straight to global. Register law (measured
// R6/R11/R12/R14): per-wave demand sits just under the 2-waves/SIMD budget; ANY
// register addition or forced-occupancy declaration spills (FETCH 76MB -> >1GB).
// This round: T5 s_setprio(1) around the LSTM MFMA cluster only (co-resident blocks
// at independent phases = the regime where setprio measured +4-7%).

typedef __attribute__((ext_vector_type(8))) short v8s;        // 8 x bf16 (4 VGPR)
typedef __attribute__((ext_vector_type(4))) float v4f;        // mfma accumulator
typedef __attribute__((ext_vector_type(4))) unsigned int v4u;

#define DEV static __device__ __forceinline__

DEV unsigned int cvtpk(float lo, float hi){
  unsigned int d;
  asm("v_cvt_pk_bf16_f32 %0, %1, %2" : "=v"(d) : "v"(lo), "v"(hi));  // RNE, S0->low
  return d;
}
DEV unsigned short f2bf(float x){ return (unsigned short)(cvtpk(x, x) & 0xffffu); }
DEV float bf2f(unsigned short h){ return __uint_as_float(((unsigned int)h) << 16); }
DEV unsigned int pkbf(float a, float b){ return cvtpk(a, b); }
DEV v4f MFMA(v8s a, v8s b, v4f c){ return __builtin_amdgcn_mfma_f32_16x16x32_bf16(a, b, c, 0, 0, 0); }
DEV v4f vzero(){ v4f z = {0.f, 0.f, 0.f, 0.f}; return z; }
DEV float relu(float x){ return x > 0.f ? x : 0.f; }
DEV float sigm(float x){ return 1.0f / (1.0f + __expf(-x)); }
DEV float tanhfast(float x){
  x = fminf(15.0f, fmaxf(-15.0f, x));
  float e = __expf(2.0f * x);
  return (e - 1.0f) / (e + 1.0f);
}
DEV uint2 pack4(v4f a, float4 b){  // (a+bias) -> relu -> 4x bf16 packed (2 cvt_pk)
  return make_uint2(cvtpk(relu(a[0]+b.x), relu(a[1]+b.y)),
                    cvtpk(relu(a[2]+b.z), relu(a[3]+b.w)));
}
union U8S { v4u u4; v8s s8; };

// ---------------- weight packing + segprep + bias (single launch) ----------------
// dst[(nt*KS+ks)*512 + lane*8 + e] = W[n][k], n = nt*16 + (lane&15), k = ks*32 + (lane>>4)*8 + e
// mode 0: direct  src[n*K + k]
// mode 1: conv    k = p9*CI + ci -> src[(n*CI+ci)*9 + p9]
// mode 2: fc      k = pos*64+ci  -> src[n*2560 + ci*40 + pos]
// mode 3: lstm    k<192: w_ih[n*192+k], else w_hh[n*128+k-192]
// mode 4: conv1   k = dy*8 + dx*2 + ci -> src[(n*2+ci)*9 + dy*3+dx]  (dx==3 / k>=K zero)
// block 3436: segprep (done-mask -> equal-length segment groups); block 3437: bias add
__global__ __launch_bounds__(256) void pack_all(
    const float* __restrict__ c1w, const float* __restrict__ c2w,
    const float* __restrict__ c3w, const float* __restrict__ fcw,
    const float* __restrict__ s1w, const float* __restrict__ s2w,
    const float* __restrict__ wih, const float* __restrict__ whh,
    const float* __restrict__ pw,
    unsigned short* __restrict__ w1p, unsigned short* __restrict__ w2p,
    unsigned short* __restrict__ w3p, unsigned short* __restrict__ fcp,
    unsigned short* __restrict__ s1p, unsigned short* __restrict__ s2p,
    unsigned short* __restrict__ lsp, unsigned short* __restrict__ pop,
    const void* __restrict__ dmask, const float* __restrict__ bih,
    const float* __restrict__ bhh, float* __restrict__ bias512,
    unsigned int* __restrict__ segs, int4* __restrict__ gtab, int* __restrict__ meta){
  __shared__ int sp[772];   // segprep scratch: cnt[257], off[257], place[257], notInt
  int b = blockIdx.x;
  int tid = threadIdx.x;
  if (b == 3437){
    bias512[tid] = bih[tid] + bhh[tid];
    bias512[tid + 256] = bih[tid + 256] + bhh[tid + 256];
    return;
  }
  if (b == 3436){
    int* cnt = sp; int* off = sp + 257; int* place = sp + 514;
    for (int idx = tid; idx < 257; idx += 256){ cnt[idx] = 0; place[idx] = 0; }
    if (tid == 0) sp[771] = 0;
    __syncthreads();
    const unsigned char* p8 = (const unsigned char*)dmask;
    int nz = 0;
    for (int idx = tid; idx < 2048; idx += 256)
      if (p8[idx * 4 + 1] | p8[idx * 4 + 2] | p8[idx * 4 + 3]) nz = 1;
    if (nz) sp[771] = 1;
    __syncthreads();
    bool m32 = (sp[771] == 0);
    const int* p32 = (const int*)dmask;
    if (tid < 128){
      int bb = tid, ts = 0;
      for (int t = 0; t < 256; ++t){
        bool d = (t == 255) ? true : (m32 ? (p32[t * 128 + bb] != 0) : (p8[t * 128 + bb] != 0));
        if (d){ atomicAdd(&cnt[t - ts + 1], 1); ts = t + 1; }
      }
    }
    __syncthreads();
    if (tid == 0){
      int acc = 0;
      for (int len = 1; len <= 256; ++len){ off[len] = acc; acc += cnt[len]; }
      int G = 0;
      for (int len = 1; len <= 256; ++len){
        int c = cnt[len], g = 0;
        while (c > 0){
          int take = c < 32 ? c : 32;
          gtab[G] = make_int4(len, off[len] + g * 32, take, 0);
          ++G; c -= 32; ++g;
        }
      }
      meta[0] = G;
    }
    __syncthreads();
    if (tid < 128){
      int bb = tid, ts = 0;
      for (int t = 0; t < 256; ++t){
        bool d = (t == 255) ? true : (m32 ? (p32[t * 128 + bb] != 0) : (p8[t * 128 + bb] != 0));
        if (d){
          int len = t - ts + 1;
          int slot = off[len] + atomicAdd(&place[len], 1);
          segs[slot] = (unsigned int)(bb | (ts << 8));
          ts = t + 1;
        }
      }
    }
    return;
  }
  const float *src, *src2 = nullptr; unsigned short* dst;
  int N, K, KS, CI, mode, rel;
  if      (b < 4)   { src=c1w; dst=w1p; N=32;  K=24;  KS=1;  CI=2;  mode=4; rel=b; }
  else if (b < 76)  { src=c2w; dst=w2p; N=64;  K=288; KS=9;  CI=32; mode=1; rel=b-4; }
  else if (b < 220) { src=c3w; dst=w3p; N=64;  K=576; KS=18; CI=64; mode=1; rel=b-76; }
  else if (b < 1500){ src=fcw; dst=fcp; N=128; K=2560;KS=80; CI=0;  mode=2; rel=b-220; }
  else if (b < 1620){ src=s1w; dst=s1p; N=64;  K=452; KS=15; CI=0;  mode=0; rel=b-1500; }
  else if (b < 1636){ src=s2w; dst=s2p; N=64;  K=64;  KS=2;  CI=0;  mode=0; rel=b-1620; }
  else if (b < 2276){ src=wih; src2=whh; dst=lsp; N=512; K=320; KS=10; CI=0; mode=3; rel=b-1636; }
  else              { src=pw;  dst=pop; N=2305;K=128; KS=4;  CI=0;  mode=0; rel=b-2276; }
  int idx = rel * 256 + tid;
  int e  = idx & 7;
  int l  = (idx >> 3) & 63;
  int fs = idx >> 9;
  int ks = fs % KS;
  int nt = fs / KS;
  int n = nt * 16 + (l & 15);
  int k = ks * 32 + (l >> 4) * 8 + e;
  float v = 0.f;
  if (n < N && k < K){
    if (mode == 0)      v = src[n * K + k];
    else if (mode == 1){ int p9 = k / CI, ci = k - p9 * CI; v = src[(n * CI + ci) * 9 + p9]; }
    else if (mode == 2){ int pos = k >> 6, ci = k & 63;     v = src[n * 2560 + ci * 40 + pos]; }
    else if (mode == 3) v = (k < 192) ? src[n * 192 + k] : src2[n * 128 + (k - 192)];
    else { int dy = k >> 3, r = k & 7, dx = r >> 1, ci = r & 1;
           if (dx < 3) v = src[(n * 2 + ci) * 9 + dy * 3 + dx]; }
  }
  dst[idx] = f2bf(v);
}

// ---------------- fused conv1/conv2/conv3 per sample (R13 config, FROZEN) ----------------
// LDS map (all zeroed once; halos never rewritten):
//  ACT1: [34 rows][20 cols][32ch] bf16  = 43520 B, swizzle ^(((p>>1)&7)<<4)
//  ACT2: [18 rows][11 cols][64ch] bf16  = 25344 B, swizzle ^(((p>>1)&7)<<4)
//  GRID: 2 x [35 rows][20 cols] u32 (ch0 lo, ch1 hi) = 2 x 2816 B, linear
#define ACT1o 0
#define ACT2o 43520
#define GRIDo 68864
#define SWZ(p) ((((p) >> 1) & 7) << 4)

__global__ __launch_bounds__(256, 2) void conv_kernel(const float* __restrict__ obs,
    const unsigned short* __restrict__ w1p, const unsigned short* __restrict__ w2p,
    const unsigned short* __restrict__ w3p,
    const float* __restrict__ b1v, const float* __restrict__ b2v, const float* __restrict__ b3v,
    unsigned short* __restrict__ act3g){
  __shared__ __align__(16) char lds[74496];
  int tid = threadIdx.x, w = tid >> 6, l = tid & 63, i = l & 15, u = l >> 4;
  int nh = w & 1, mh = w >> 1;
  const v8s* W1 = (const v8s*)w1p;
  const v8s* W2 = (const v8s*)w2p;
  const v8s* W3 = (const v8s*)w3p;
  v8s w1f0 = W1[l], w1f1 = W1[64 + l];              // persistent conv1 weights
  float4 bc1a = *(const float4*)&b1v[u * 4];
  float4 bc1b = *(const float4*)&b1v[16 + u * 4];
  float4 bc2a = *(const float4*)&b2v[nh * 32 + u * 4];
  float4 bc2b = *(const float4*)&b2v[nh * 32 + 16 + u * 4];
  float4 bc3a = *(const float4*)&b3v[nh * 32 + u * 4];
  float4 bc3b = *(const float4*)&b3v[nh * 32 + 16 + u * 4];
  // zero ALL of LDS once (covers halos + grid pad rows)
  for (int idx = tid; idx < 18624; idx += 256) *(unsigned int*)(lds + idx * 4) = 0u;
  // staging offsets: thread tid<144 owns pixels 4tid..4tid+3 -> padded [r+1][c+1]
  int soff[4];
  #pragma unroll
  for (int j = 0; j < 4; ++j){
    int p = tid * 4 + j, r = p / 18, c = p - r * 18;
    soff[j] = ((r + 1) * 20 + (c + 1)) * 4;
  }
  __syncthreads();
  long sbase = (long)blockIdx.x * 64;
  if (tid < 144){
    const float4* gp = (const float4*)(obs + sbase * 1604 + 452);
    float4 a = gp[tid], b = gp[tid + 144];
    *(unsigned int*)(lds + GRIDo + soff[0]) = pkbf(a.x, b.x);
    *(unsigned int*)(lds + GRIDo + soff[1]) = pkbf(a.y, b.y);
    *(unsigned int*)(lds + GRIDo + soff[2]) = pkbf(a.z, b.z);
    *(unsigned int*)(lds + GRIDo + soff[3]) = pkbf(a.w, b.w);
  }
  __syncthreads();

  // conv3 per-wave geometry (it-invariant): one 16-pos tile per wave pair + tail on mh==0
  int pos3_0 = (mh ? 1 : 0) * 16 + i;                 // slot 0 pos (always < 32)
  int pos3_1r = 32 + i;                               // slot 1 raw pos (mh==0 only)
  int pos3_1 = pos3_1r > 39 ? 39 : pos3_1r;
  int oh30 = pos3_0 / 5, ow30 = pos3_0 - oh30 * 5;
  int oh31 = pos3_1 / 5, ow31 = pos3_1 - oh31 * 5;
  int pr3_0 = (2 * oh30) * 11 + 2 * ow30;
  int pr3_1 = (2 * oh31) * 11 + 2 * ow31;

  for (int it = 0; it < 64; ++it){
    long s = sbase + it;
    int gbo = GRIDo + (it & 1) * 2816;
    // conv2 weight loads (phase-local; LICM blocked)
    int z2; asm("s_mov_b32 %0, 0" : "=s"(z2) : "s"(it));
    v8s w2f[2][9];
    #pragma unroll
    for (int jj = 0; jj < 2; ++jj)
      #pragma unroll
      for (int t = 0; t < 9; ++t) w2f[jj][t] = W2[((nh * 2 + jj) * 9 + t) * 64 + l + z2];
    // prefetch next sample's grid
    float4 pa, pb; bool pf = (it < 63) && (tid < 144);
    if (pf){
      const float4* gp = (const float4*)(obs + (s + 1) * 1604 + 452);
      pa = gp[tid]; pb = gp[tid + 144];
    }
    // ---- conv1: fragments straight from padded grid; 9 pos-tiles per wave ----
    #pragma unroll
    for (int k = 0; k < 9; ++k){
      int ntl = w + 4 * k;
      int pos = ntl * 16 + i;
      int oh = pos / 18, ow = pos - oh * 18;
      int glin = gbo + ((oh + u) * 20 + ow) * 4;      // row oh+u, cols ow..ow+3
      U8S gv;
      gv.u4.x = *(const unsigned int*)(lds + glin);
      gv.u4.y = *(const unsigned int*)(lds + glin + 4);
      gv.u4.z = *(const unsigned int*)(lds + glin + 8);
      gv.u4.w = *(const unsigned int*)(lds + glin + 12);
      v4f a0 = MFMA(w1f0, gv.s8, vzero());
      v4f a1 = MFMA(w1f1, gv.s8, vzero());
      int p1 = (oh + 1) * 20 + (ow + 1);
      int sA = SWZ(p1);
      *(uint2*)(lds + ACT1o + ((p1 * 64 + u * 8) ^ sA))      = pack4(a0, bc1a);
      *(uint2*)(lds + ACT1o + ((p1 * 64 + 32 + u * 8) ^ sA)) = pack4(a1, bc1b);
    }
    __syncthreads();   // B: ACT1 visible; grid reads done
    // ---- conv2: 16x9 out, 64 ch; wave (nh,mh): ch-pair nh, pos parity mh ----
    for (int ntl = mh; ntl < 9; ntl += 2){
      int pos2 = ntl * 16 + i;
      int oh = pos2 / 9, ow = pos2 - oh * 9;
      int pr0 = (2 * oh) * 20 + 2 * ow;
      v4f a0 = vzero(), a1 = vzero();
      #pragma unroll
      for (int dy = 0; dy < 3; ++dy)
        #pragma unroll
        for (int dx = 0; dx < 3; ++dx){
          int p = pr0 + dy * 20 + dx;
          int byte = (p * 64 + u * 16) ^ SWZ(p);
          v8s bf = *(const v8s*)(lds + ACT1o + byte);
          a0 = MFMA(w2f[0][dy * 3 + dx], bf, a0);
          a1 = MFMA(w2f[1][dy * 3 + dx], bf, a1);
        }
      int p2 = (oh + 1) * 11 + (ow + 1);
      int sB = SWZ(p2);
      *(uint2*)(lds + ACT2o + ((p2 * 128 + nh * 64 + u * 8) ^ sB))      = pack4(a0, bc2a);
      *(uint2*)(lds + ACT2o + ((p2 * 128 + nh * 64 + 32 + u * 8) ^ sB)) = pack4(a1, bc2b);
    }
    // stage next sample's grid into the other buffer (visible after barrier C)
    if (pf){
      int gbn = GRIDo + ((it + 1) & 1) * 2816;
      *(unsigned int*)(lds + gbn + soff[0]) = pkbf(pa.x, pb.x);
      *(unsigned int*)(lds + gbn + soff[1]) = pkbf(pa.y, pb.y);
      *(unsigned int*)(lds + gbn + soff[2]) = pkbf(pa.z, pb.z);
      *(unsigned int*)(lds + gbn + soff[3]) = pkbf(pa.w, pb.w);
    }
    __syncthreads();   // C: ACT2 + next grid visible
    // ---- conv3: ch-pair nh x pos-split mh (mh0: tiles 0,2; mh1: tile 1); K in 2 chunks ----
    {
      int z3; asm("s_mov_b32 %0, 0" : "=s"(z3) : "s"(it));
      v4f c300 = vzero(), c301 = vzero(), c310 = vzero(), c311 = vzero();
      #pragma unroll
      for (int ksh = 0; ksh < 2; ++ksh){
        const int t0 = ksh * 5, tc = ksh ? 4 : 5;
        v8s w3q[2][5][2];
        #pragma unroll
        for (int j = 0; j < 2; ++j)
          #pragma unroll
          for (int tt = 0; tt < 5; ++tt){
            if (tt < tc){
              #pragma unroll
              for (int h = 0; h < 2; ++h)
                w3q[j][tt][h] = W3[((2 * nh + j) * 18 + 2 * (t0 + tt) + h) * 64 + l + z3];
            }
          }
        #pragma unroll
        for (int tt = 0; tt < 5; ++tt){
          if (tt < tc){
            int tap = t0 + tt, dy = tap / 3, dx = tap - dy * 3;
            int dpp = dy * 11 + dx;
            #pragma unroll
            for (int h = 0; h < 2; ++h){
              {
                int p = pr3_0 + dpp;
                int byte = (p * 128 + h * 64 + u * 16) ^ SWZ(p);
                v8s bf = *(const v8s*)(lds + ACT2o + byte);
                c300 = MFMA(w3q[0][tt][h], bf, c300);
                c301 = MFMA(w3q[1][tt][h], bf, c301);
              }
              if (mh == 0){
                int p = pr3_1 + dpp;
                int byte = (p * 128 + h * 64 + u * 16) ^ SWZ(p);
                v8s bf = *(const v8s*)(lds + ACT2o + byte);
                c310 = MFMA(w3q[0][tt][h], bf, c310);
                c311 = MFMA(w3q[1][tt][h], bf, c311);
              }
            }
          }
        }
      }
      unsigned short* dg = act3g + s * 2560;
      *(uint2*)(dg + pos3_0 * 64 + nh * 32 + u * 4)      = pack4(c300, bc3a);
      *(uint2*)(dg + pos3_0 * 64 + nh * 32 + 16 + u * 4) = pack4(c301, bc3b);
      if (mh == 0 && pos3_1r < 40){
        *(uint2*)(dg + pos3_1r * 64 + nh * 32 + u * 4)      = pack4(c310, bc3a);
        *(uint2*)(dg + pos3_1r * 64 + nh * 32 + 16 + u * 4) = pack4(c311, bc3b);
      }
    }
    // no trailing barrier: conv3's ACT2 reads are protected by next iteration's barrier B
  }
}

// ---------------- embed: fc (blocks 0..511) + scalar MLP (blocks 512..1535) ----------------
__global__ __launch_bounds__(256) void embed_kernel(
    const unsigned short* __restrict__ act3g, const unsigned short* __restrict__ fcp,
    const float* __restrict__ fcb,
    const float* __restrict__ obs, const unsigned short* __restrict__ s1p,
    const unsigned short* __restrict__ s2p,
    const float* __restrict__ s1b, const float* __restrict__ s2b,
    unsigned short* __restrict__ emb){
  __shared__ __align__(16) unsigned short shb[17920];
  int bid = blockIdx.x;
  int tid = threadIdx.x, w = tid >> 6, l = tid & 63, i = l & 15, u = l >> 4;
  if (bid < 512){
    // ---- fc: act3(2560) -> 128, relu -> emb[:,0:128] ----
    unsigned short* al = shb;                        // [64 rows][264]
    long s0 = (long)bid * 64;
    v4f acc[4][2];
    #pragma unroll
    for (int mt = 0; mt < 4; ++mt){ acc[mt][0] = vzero(); acc[mt][1] = vzero(); }
    const v8s* F = (const v8s*)fcp;
    for (int kc = 0; kc < 10; ++kc){
      __syncthreads();
      for (int idx = tid; idx < 64 * 32; idx += 256){
        int r = idx >> 5, q = idx & 31;
        *(v8s*)&al[r * 264 + q * 8] = *(const v8s*)&act3g[(s0 + r) * 2560 + kc * 256 + q * 8];
      }
      __syncthreads();
      #pragma unroll
      for (int ksl = 0; ksl < 8; ++ksl){
        v8s b0 = F[((w * 2 + 0) * 80 + kc * 8 + ksl) * 64 + l];
        v8s b1 = F[((w * 2 + 1) * 80 + kc * 8 + ksl) * 64 + l];
        #pragma unroll
        for (int mt = 0; mt < 4; ++mt){
          v8s aa = *(const v8s*)&al[(mt * 16 + i) * 264 + ksl * 32 + u * 8];
          acc[mt][0] = MFMA(aa, b0, acc[mt][0]);
          acc[mt][1] = MFMA(aa, b1, acc[mt][1]);
        }
      }
    }
    float fb0 = fcb[(w * 2) * 16 + i], fb1 = fcb[(w * 2 + 1) * 16 + i];
    #pragma unroll
    for (int mt = 0; mt < 4; ++mt)
      #pragma unroll
      for (int r = 0; r < 4; ++r){
        float v0 = relu(acc[mt][0][r] + fb0);
        float v1 = relu(acc[mt][1][r] + fb1);
        emb[(s0 + mt * 16 + u * 4 + r) * 192 + (w * 2) * 16 + i] = f2bf(v0);
        emb[(s0 + mt * 16 + u * 4 + r) * 192 + (w * 2 + 1) * 16 + i] = f2bf(v1);
      }
  } else {
    // ---- scalar MLP: obs[:,:452] -> 64 -> 64 -> emb[:,128:192] ----
    unsigned short* xl = shb;                        // [32 rows][488]
    unsigned short* h1 = shb + 15616;                // [32 rows][72]
    long s0 = (long)(bid - 512) * 32;
    for (int idx = tid; idx < 32 * 113; idx += 256){
      int r = idx / 113, q = idx - r * 113;
      float4 v = *(const float4*)&obs[(s0 + r) * 1604 + q * 4];
      *(uint2*)&xl[r * 488 + q * 4] = make_uint2(pkbf(v.x, v.y), pkbf(v.z, v.w));
    }
    for (int idx = tid; idx < 32 * 28; idx += 256){   // zero pad cols 452..479
      int r = idx / 28, k = 452 + (idx - r * 28);
      xl[r * 488 + k] = 0;
    }
    __syncthreads();
    v4f acc0 = vzero(), acc1 = vzero();
    const v8s* F1 = (const v8s*)s1p;
    #pragma unroll
    for (int ks = 0; ks < 15; ++ks){
      v8s bb = F1[(w * 15 + ks) * 64 + l];
      v8s aa0 = *(const v8s*)&xl[(0 * 16 + i) * 488 + ks * 32 + u * 8];
      v8s aa1 = *(const v8s*)&xl[(1 * 16 + i) * 488 + ks * 32 + u * 8];
      acc0 = MFMA(aa0, bb, acc0);
      acc1 = MFMA(aa1, bb, acc1);
    }
    float b1 = s1b[w * 16 + i];
    #pragma unroll
    for (int r = 0; r < 4; ++r){
      float v0 = relu(acc0[r] + b1);
      float v1 = relu(acc1[r] + b1);
      h1[(u * 4 + r) * 72 + w * 16 + i] = f2bf(v0);
      h1[(16 + u * 4 + r) * 72 + w * 16 + i] = f2bf(v1);
    }
    __syncthreads();
    v4f a20 = vzero(), a21 = vzero();
    const v8s* F2 = (const v8s*)s2p;
    #pragma unroll
    for (int ks = 0; ks < 2; ++ks){
      v8s bb = F2[(w * 2 + ks) * 64 + l];
      v8s aa0 = *(const v8s*)&h1[(0 * 16 + i) * 72 + ks * 32 + u * 8];
      v8s aa1 = *(const v8s*)&h1[(1 * 16 + i) * 72 + ks * 32 + u * 8];
      a20 = MFMA(aa0, bb, a20);
      a21 = MFMA(aa1, bb, a21);
    }
    float b2 = s2b[w * 16 + i];
    #pragma unroll
    for (int r = 0; r < 4; ++r){
      float v0 = relu(a20[r] + b2);
      float v1 = relu(a21[r] + b2);
      emb[(s0 + u * 4 + r) * 192 + 128 + w * 16 + i] = f2bf(v0);
      emb[(s0 + 16 + u * 4 + r) * 192 + 128 + w * 16 + i] = f2bf(v1);
    }
  }
}

// ---------------- LSTM over segment groups: M=32 segs, N=512 gates, K=320 ----------------
__global__ __launch_bounds__(512) void lstm_kernel(
    const unsigned short* __restrict__ emb, const unsigned short* __restrict__ lstmp,
    const float* __restrict__ bias512,
    const float* __restrict__ h0, const float* __restrict__ c0,
    const unsigned int* __restrict__ segs, const int4* __restrict__ gtab,
    const int* __restrict__ meta,
    unsigned short* __restrict__ outsb, float* __restrict__ hf, float* __restrict__ cf){
  int grp = blockIdx.x;
  if (grp >= meta[0]) return;
  int4 gd = gtab[grp];
  int len = gd.x, base = gd.y, nseg = gd.z;
  __shared__ __align__(16) unsigned short hbuf[2][32 * 136];
  __shared__ int sb[32], st[32];
  int tid = threadIdx.x, w = tid >> 6, l = tid & 63, i = l & 15, u = l >> 4;
  if (tid < 32){
    unsigned int sv = segs[base + (tid < nseg ? tid : 0)];
    sb[tid] = (int)(sv & 127u);
    st[tid] = (int)((sv >> 8) & 255u);
  }
  __syncthreads();
  int j = w * 16 + i;
  float cst[2][4];
  #pragma unroll
  for (int mt = 0; mt < 2; ++mt)
    #pragma unroll
    for (int r = 0; r < 4; ++r){
      int slot = mt * 16 + u * 4 + r;
      float cv = 0.f, hv = 0.f;
      if (st[slot] == 0){ cv = c0[sb[slot] * 128 + j]; hv = h0[sb[slot] * 128 + j]; }
      cst[mt][r] = cv;
      hbuf[0][slot * 136 + j] = f2bf(hv);
    }
  float bi = bias512[j], bff = bias512[128 + j], bg = bias512[256 + j], bo = bias512[384 + j];
  int bA0 = sb[i], tA0 = st[i];
  int bA1 = sb[16 + i], tA1 = st[16 + i];
  __syncthreads();
  const v8s* LP = (const v8s*)lstmp;
  for (int step = 0; step < len; ++step){
    int pb = step & 1;
    v4f gi0 = vzero(), gi1 = vzero(), gf0 = vzero(), gf1 = vzero();
    v4f gg0 = vzero(), gg1 = vzero(), go0 = vzero(), go1 = vzero();
    __builtin_amdgcn_s_setprio(1);   // T5: favor this wave's MFMA cluster vs co-resident blocks
    #pragma unroll
    for (int ks = 0; ks < 10; ++ks){
      v8s a0, a1;
      if (ks < 6){
        a0 = *(const v8s*)&emb[((long)(tA0 + step) * 128 + bA0) * 192 + ks * 32 + u * 8];
        a1 = *(const v8s*)&emb[((long)(tA1 + step) * 128 + bA1) * 192 + ks * 32 + u * 8];
      } else {
        int koff = (ks - 6) * 32 + u * 8;
        a0 = *(const v8s*)&hbuf[pb][i * 136 + koff];
        a1 = *(const v8s*)&hbuf[pb][(16 + i) * 136 + koff];
      }
      v8s b_i = LP[((w) * 10 + ks) * 64 + l];
      v8s b_f = LP[((w + 8) * 10 + ks) * 64 + l];
      v8s b_g = LP[((w + 16) * 10 + ks) * 64 + l];
      v8s b_o = LP[((w + 24) * 10 + ks) * 64 + l];
      gi0 = MFMA(a0, b_i, gi0); gi1 = MFMA(a1, b_i, gi1);
      gf0 = MFMA(a0, b_f, gf0); gf1 = MFMA(a1, b_f, gf1);
      gg0 = MFMA(a0, b_g, gg0); gg1 = MFMA(a1, b_g, gg1);
      go0 = MFMA(a0, b_o, go0); go1 = MFMA(a1, b_o, go1);
    }
    __builtin_amdgcn_s_setprio(0);
    #pragma unroll
    for (int mt = 0; mt < 2; ++mt)
      #pragma unroll
      for (int r = 0; r < 4; ++r){
        int slot = mt * 16 + u * 4 + r;
        float giv = mt ? gi1[r] : gi0[r];
        float gfv = mt ? gf1[r] : gf0[r];
        float ggv = mt ? gg1[r] : gg0[r];
        float gov = mt ? go1[r] : go0[r];
        float iv = sigm(giv + bi);
        float fv = sigm(gfv + bff);
        float gv = tanhfast(ggv + bg);
        float ov = sigm(gov + bo);
        float cv = fv * cst[mt][r] + iv * gv;
        cst[mt][r] = cv;
        float hv = ov * tanhfast(cv);
        unsigned short hb = f2bf(hv);
        hbuf[pb ^ 1][slot * 136 + j] = hb;
        if (slot < nseg){
          outsb[((long)(st[slot] + step) * 128 + sb[slot]) * 128 + j] = hb;
          if (st[slot] + len == 256 && step == len - 1){
            hf[sb[slot] * 128 + j] = hv;
            cf[sb[slot] * 128 + j] = cv;
          }
        }
      }
    __syncthreads();
  }
}

// ---------------- heads: logits = outs @ pol_w.T + pol_b; values fused ----------------
__global__ __launch_bounds__(256) void heads_kernel(const unsigned short* __restrict__ outsb,
    const unsigned short* __restrict__ polp, const float* __restrict__ polb,
    const float* __restrict__ vw, const float* __restrict__ vb,
    float* __restrict__ logits, float* __restrict__ values){
  __shared__ __align__(16) unsigned short al[64 * 136];
  int tid = threadIdx.x, w = tid >> 6, l = tid & 63, i = l & 15, u = l >> 4;
  long s0 = (long)blockIdx.x * 64;
  for (int idx = tid; idx < 64 * 16; idx += 256){
    int r = idx >> 4, q = idx & 15;
    *(v8s*)&al[r * 136 + q * 8] = *(const v8s*)&outsb[(s0 + r) * 128 + q * 8];
  }
  __syncthreads();
  v8s af[4][4];
  #pragma unroll
  for (int mt = 0; mt < 4; ++mt)
    #pragma unroll
    for (int ks = 0; ks < 4; ++ks)
      af[mt][ks] = *(const v8s*)&al[(mt * 16 + i) * 136 + ks * 32 + u * 8];
  const v8s* P = (const v8s*)polp;
  for (int nt = w; nt < 145; nt += 4){
    v4f acc[4];
    #pragma unroll
    for (int mt = 0; mt < 4; ++mt) acc[mt] = vzero();
    #pragma unroll
    for (int ks = 0; ks < 4; ++ks){
      v8s bb = P[(nt * 4 + ks) * 64 + l];
      #pragma unroll
      for (int mt = 0; mt < 4; ++mt) acc[mt] = MFMA(af[mt][ks], bb, acc[mt]);
    }
    int n = nt * 16 + i;
    if (n < 2305){
      float pbv = polb[n];
      #pragma unroll
      for (int mt = 0; mt < 4; ++mt)
        #pragma unroll
        for (int r = 0; r < 4; ++r)
          logits[(s0 + mt * 16 + u * 4 + r) * 2305 + n] = acc[mt][r] + pbv;
    }
  }
  // fused values: wave w covers rows w*16+i; lane group u handles cols g*32+u*8
  float vacc = 0.f;
  #pragma unroll
  for (int g = 0; g < 4; ++g){
    float4 vA = *(const float4*)&vw[g * 32 + u * 8];
    float4 vB = *(const float4*)&vw[g * 32 + u * 8 + 4];
    v8s xv = *(const v8s*)&al[(w * 16 + i) * 136 + g * 32 + u * 8];
    vacc += bf2f((unsigned short)xv[0]) * vA.x + bf2f((unsigned short)xv[1]) * vA.y
          + bf2f((unsigned short)xv[2]) * vA.z + bf2f((unsigned short)xv[3]) * vA.w
          + bf2f((unsigned short)xv[4]) * vB.x + bf2f((unsigned short)xv[5]) * vB.y
          + bf2f((unsigned short)xv[6]) * vB.z + bf2f((unsigned short)xv[7]) * vB.w;
  }
  vacc += __shfl_xor(vacc, 16);
  vacc += __shfl_xor(vacc, 32);
  if (u == 0) values[s0 + w * 16 + i] = vacc + vb[0];
}

// ---------------- launcher ----------------
extern "C" void kernel_launch(void* const* d_in, const int* in_sizes, int n_in,
                              void* d_out, int out_size, void* d_ws, size_t ws_size,
                              hipStream_t stream){
  (void)in_sizes; (void)n_in; (void)out_size; (void)ws_size;
  const float* obs = (const float*)d_in[0];
  const float* h0  = (const float*)d_in[1];
  const float* c0  = (const float*)d_in[2];
  const void*  dm  = d_in[3];
  const float* c1w = (const float*)d_in[4];  const float* c1b = (const float*)d_in[5];
  const float* c2w = (const float*)d_in[6];  const float* c2b = (const float*)d_in[7];
  const float* c3w = (const float*)d_in[8];  const float* c3b = (const float*)d_in[9];
  const float* fcw = (const float*)d_in[10]; const float* fcb = (const float*)d_in[11];
  const float* s1w = (const float*)d_in[12]; const float* s1b = (const float*)d_in[13];
  const float* s2w = (const float*)d_in[14]; const float* s2b = (const float*)d_in[15];
  const float* wih = (const float*)d_in[16]; const float* whh = (const float*)d_in[17];
  const float* bih = (const float*)d_in[18]; const float* bhh = (const float*)d_in[19];
  const float* pw  = (const float*)d_in[20]; const float* pb  = (const float*)d_in[21];
  const float* vw  = (const float*)d_in[22]; const float* vb  = (const float*)d_in[23];

  char* ws = (char*)d_ws;
  size_t off = 0;
  auto take = [&](size_t sz)->char*{
    char* p = ws + off; off = (off + sz + 255) & ~(size_t)255; return p;
  };
  unsigned short* emb    = (unsigned short*)take(32768UL * 192 * 2);
  unsigned short* outsb  = (unsigned short*)take(32768UL * 128 * 2);
  unsigned short* w1p    = (unsigned short*)take(1024UL * 2);
  unsigned short* w2p    = (unsigned short*)take(18432UL * 2);
  unsigned short* w3p    = (unsigned short*)take(36864UL * 2);
  unsigned short* fcp    = (unsigned short*)take(327680UL * 2);
  unsigned short* s1p    = (unsigned short*)take(30720UL * 2);
  unsigned short* s2p    = (unsigned short*)take(4096UL * 2);
  unsigned short* lsp    = (unsigned short*)take(163840UL * 2);
  unsigned short* pop    = (unsigned short*)take(296960UL * 2);
  float*          b512   = (float*)take(512UL * 4);
  unsigned int*   segs   = (unsigned int*)take(32768UL * 4);
  int4*           gtab   = (int4*)take(1280UL * 16);
  int*            meta   = (int*)take(256);

  float* outp   = (float*)d_out;
  float* logits = outp;
  float* values = outp + 75530240L;
  float* hf     = outp + 75563008L;
  float* cf     = outp + 75579392L;
  unsigned short* act3g = (unsigned short*)d_out;  // scratch overlay, dead before heads writes

  dim3 b256(256), b512t(512);
  pack_all<<<dim3(3438), b256, 0, stream>>>(c1w, c2w, c3w, fcw, s1w, s2w, wih, whh, pw,
                                            w1p, w2p, w3p, fcp, s1p, s2p, lsp, pop,
                                            dm, bih, bhh, b512, segs, gtab, meta);
  conv_kernel<<<dim3(512), b256, 0, stream>>>(obs, w1p, w2p, w3p, c1b, c2b, c3b, act3g);
  embed_kernel<<<dim3(1536), b256, 0, stream>>>(act3g, fcp, fcb, obs, s1p, s2p, s1b, s2b, emb);
  lstm_kernel<<<dim3(1280), b512t, 0, stream>>>(emb, lsp, b512, h0, c0, segs, gtab, meta,
                                                outsb, hf, cf);
  heads_kernel<<<dim3(512), b256, 0, stream>>>(outsb, pop, pb, vw, vb, logits, values);
}